// Round 4
// baseline (628.343 us; speedup 1.0000x reference)
//
#include <hip/hip_runtime.h>
#include <hip/hip_bf16.h>
#include <stdint.h>

typedef unsigned short u16;
typedef __attribute__((ext_vector_type(8))) short short8;
typedef __attribute__((ext_vector_type(4))) float float4v;

#define NNODES 11201
#define MPAD   11264
#define EEDGES 100000
#define RREL   5
#define DDIM   512
#define XLW    2560      // RREL*DDIM
#define FRAMES 1200
#define OUTC   1712      // FRAMES + DDIM

__device__ __forceinline__ float bf2f(u16 h) {
    return __uint_as_float(((uint32_t)h) << 16);
}
__device__ __forceinline__ u16 f2bf(float f) {
    uint32_t x = __float_as_uint(f);
    x += 0x7fffu + ((x >> 16) & 1u);   // RNE
    return (u16)(x >> 16);
}
__device__ __forceinline__ float fast_tanh(float v) {
    v = fminf(fmaxf(v, -10.f), 10.f);
    float ex = __expf(2.f * v);
    return (ex - 1.f) / (ex + 1.f);
}

// ---------------- CSR build ----------------
__global__ void hist_k(const int* __restrict__ rows, int* __restrict__ counts) {
    int tid = blockIdx.x * 256 + threadIdx.x;
    if (tid >= RREL * EEDGES) return;
    int r = tid / EEDGES;
    atomicAdd(&counts[r * NNODES + rows[tid]], 1);
}

// single-pass scan: 1024 threads, 11 elems/thread; writes offs AND cursor
__global__ __launch_bounds__(1024) void scan_offsets(const int* __restrict__ counts,
                                                     int* __restrict__ offs,
                                                     int* __restrict__ cursor) {
    const int PER = 11;          // 1024*11 = 11264 >= NNODES
    int r = blockIdx.x;
    const int* c = counts + (size_t)r * NNODES;
    int* o = offs + (size_t)r * (NNODES + 1);
    int* cur = cursor + (size_t)r * NNODES;
    __shared__ int wsum[16];
    const int lane = threadIdx.x & 63, wid = threadIdx.x >> 6;
    int base = threadIdx.x * PER;
    int v[PER];
    int s = 0;
    #pragma unroll
    for (int t = 0; t < PER; ++t) {
        int idx = base + t;
        v[t] = (idx < NNODES) ? c[idx] : 0;
        s += v[t];
    }
    int incl = s;
    #pragma unroll
    for (int d = 1; d < 64; d <<= 1) {
        int t = __shfl_up(incl, d, 64);
        if (lane >= d) incl += t;
    }
    if (lane == 63) wsum[wid] = incl;
    __syncthreads();
    if (wid == 0) {
        int wv = (lane < 16) ? wsum[lane] : 0;
        #pragma unroll
        for (int d = 1; d < 16; d <<= 1) {
            int t = __shfl_up(wv, d, 64);
            if (lane >= d) wv += t;
        }
        if (lane < 16) wsum[lane] = wv;
    }
    __syncthreads();
    int run = incl - s + ((wid > 0) ? wsum[wid - 1] : 0);   // exclusive prefix
    #pragma unroll
    for (int t = 0; t < PER; ++t) {
        int idx = base + t;
        if (idx < NNODES) { o[idx] = run; cur[idx] = run; }
        run += v[t];
    }
    if (threadIdx.x == 1023) o[NNODES] = run;
}

__global__ void scatter_k(const int* __restrict__ rows, const int* __restrict__ cols,
                          const float* __restrict__ vals, int* __restrict__ cursor,
                          int* __restrict__ colS, float* __restrict__ valS) {
    int tid = blockIdx.x * 256 + threadIdx.x;
    if (tid >= RREL * EEDGES) return;
    int r = tid / EEDGES;
    int row = rows[tid];
    int pos = atomicAdd(&cursor[r * NNODES + row], 1);
    colS[(size_t)r * EEDGES + pos] = cols[tid];
    valS[(size_t)r * EEDGES + pos] = vals[tid];
}

// ---------------- input assembly: build_x (fp32->bf16 gather) + tsp pad, one dispatch ----
#define BX_BLOCKS 5601     // ceil(NNODES*128/256)
__global__ void prep_inputs(const float* __restrict__ frame_emb,
                            const float* __restrict__ role_emb,
                            const int* __restrict__ fe_ids,
                            const float* __restrict__ ts,
                            u16* __restrict__ x, u16* __restrict__ tsp) {
    int bid = blockIdx.x;
    if (bid < BX_BLOCKS) {
        int t = bid * 256 + threadIdx.x;
        int row = t >> 7, c4 = (t & 127) << 2;
        if (row >= NNODES) return;
        const float* src = (row < FRAMES) ? (frame_emb + (size_t)row * DDIM)
                                          : (role_emb + (size_t)fe_ids[row - FRAMES] * DDIM);
        float4 v = *(const float4*)(src + c4);
        ushort4 o = { f2bf(v.x), f2bf(v.y), f2bf(v.z), f2bf(v.w) };
        *(ushort4*)(x + (size_t)row * DDIM + c4) = o;
    } else {
        int t = (bid - BX_BLOCKS) * 256 + threadIdx.x;   // < 65536
        int row = t >> 9, c4 = (t & 511) << 2;
        ushort4 o = {0, 0, 0, 0};
        if (row < 32) {
            float4 v = *(const float4*)(ts + (size_t)row * 2048 + c4);
            o = ushort4{ f2bf(v.x), f2bf(v.y), f2bf(v.z), f2bf(v.w) };
        }
        *(ushort4*)(tsp + (size_t)row * 2048 + c4) = o;
    }
}

// ---------------- all 6 weight transposes (fp32 -> bf16) in one dispatch ---------------
__global__ void transpose_all(const float* __restrict__ w0, const float* __restrict__ w1,
                              const float* __restrict__ s1, const float* __restrict__ s2,
                              const float* __restrict__ f1, const float* __restrict__ f2,
                              u16* __restrict__ w0t, u16* __restrict__ w1t,
                              u16* __restrict__ s1t, u16* __restrict__ s2t,
                              u16* __restrict__ f1t, u16* __restrict__ f2t) {
    int b = blockIdx.x;
    const float* src; u16* dst;
    int cols, ldOut, bx, by;
    size_t zcol = 0;
    if (b < 1280) {
        int rel = b >> 8, rem = b & 255;
        src = w0 + (size_t)rel * 262144; dst = w0t;
        cols = 512; ldOut = XLW; zcol = (size_t)rel * 512;
        bx = rem & 15; by = rem >> 4;
    } else if (b < 2560) {
        b -= 1280;
        int rel = b >> 8, rem = b & 255;
        src = w1 + (size_t)rel * 262144; dst = w1t;
        cols = 512; ldOut = XLW; zcol = (size_t)rel * 512;
        bx = rem & 15; by = rem >> 4;
    } else if (b < 6656) {
        b -= 2560;
        src = s1; dst = s1t; cols = 2048; ldOut = 2048;
        bx = b & 63; by = b >> 6;
    } else if (b < 7680) {
        b -= 6656;
        src = s2; dst = s2t; cols = 512; ldOut = 2048;
        bx = b & 15; by = b >> 4;
    } else if (b < 7936) {
        b -= 7680;
        src = f1; dst = f1t; cols = 512; ldOut = 512;
        bx = b & 15; by = b >> 4;
    } else {
        b -= 7936;
        src = f2; dst = f2t; cols = 512; ldOut = 512;
        bx = b & 15; by = b >> 4;
    }
    __shared__ u16 tile[32][33];
    int c0 = bx * 32, r0 = by * 32;
    int tx = threadIdx.x & 31, ty = threadIdx.x >> 5;   // 256 threads
    #pragma unroll
    for (int i = 0; i < 4; ++i) {
        int rr = ty + i * 8;
        tile[rr][tx] = f2bf(src[(size_t)(r0 + rr) * cols + c0 + tx]);
    }
    __syncthreads();
    #pragma unroll
    for (int i = 0; i < 4; ++i) {
        int rr = ty + i * 8;
        dst[(size_t)(c0 + rr) * ldOut + zcol + r0 + tx] = tile[tx][rr];
    }
}

// ------- unified split-K BT-GEMM, fp32 atomic accumulate, swizzled LDS (conflict-free) --
// C[m][n] += sum_{k in z-chunk} A[m][k] * Bt[n][k]
template<bool GUARDM>
__global__ __launch_bounds__(256)
void gemm_sk(const u16* __restrict__ A, const u16* __restrict__ Bt,
             float* __restrict__ Cf, int K, int Kc,
             int lda, int ldb, int ldc, int mGuard)
{
    __shared__ u16 As[128 * 32];
    __shared__ u16 Bs[128 * 32];
    const int tid = threadIdx.x;
    const int wave = tid >> 6, lane = tid & 63;
    const int m0 = blockIdx.y * 128, n0 = blockIdx.x * 128;
    const int kb = blockIdx.z * Kc;
    const int srow = lane >> 2;                         // 0..15 row within stage
    const int schunk = ((lane & 3) - (lane >> 4)) & 3;  // global k-chunk this lane fetches
    const int skoff = schunk << 3;                      // u16 offset
    const int fr = lane & 15, quad = lane >> 4;
    const int pa = ((quad + (fr >> 2)) & 3) << 3;       // swizzled LDS chunk position (u16)
    const int wm = (wave & 1) << 6, wn = (wave >> 1) << 6;
    float4v acc[4][4] = {};

    for (int k0 = kb; k0 < kb + Kc; k0 += 32) {
        #pragma unroll
        for (int i = 0; i < 2; ++i) {
            const int rb = (wave + i * 4) << 4;
            const u16* ga = A  + (size_t)(m0 + rb + srow) * lda + (k0 + skoff);
            const u16* gb = Bt + (size_t)(n0 + rb + srow) * ldb + (k0 + skoff);
            __builtin_amdgcn_global_load_lds(
                (const __attribute__((address_space(1))) unsigned int*)ga,
                (__attribute__((address_space(3))) unsigned int*)(As + rb * 32), 16, 0, 0);
            __builtin_amdgcn_global_load_lds(
                (const __attribute__((address_space(1))) unsigned int*)gb,
                (__attribute__((address_space(3))) unsigned int*)(Bs + rb * 32), 16, 0, 0);
        }
        __syncthreads();
        short8 a[4], b[4];
        #pragma unroll
        for (int t = 0; t < 4; ++t)
            a[t] = *(const short8*)(As + ((wm + t * 16 + fr) << 5) + pa);
        #pragma unroll
        for (int t = 0; t < 4; ++t)
            b[t] = *(const short8*)(Bs + ((wn + t * 16 + fr) << 5) + pa);
        #pragma unroll
        for (int i = 0; i < 4; ++i)
            #pragma unroll
            for (int j = 0; j < 4; ++j)
                acc[i][j] = __builtin_amdgcn_mfma_f32_16x16x32_bf16(a[i], b[j], acc[i][j], 0, 0, 0);
        __syncthreads();
    }

    #pragma unroll
    for (int i = 0; i < 4; ++i)
        #pragma unroll
        for (int j = 0; j < 4; ++j) {
            const int n = n0 + wn + j * 16 + fr;
            #pragma unroll
            for (int rg = 0; rg < 4; ++rg) {
                const int m = m0 + wm + i * 16 + (quad << 2) + rg;
                if (!GUARDM || m < mGuard)
                    atomicAdd(&Cf[(size_t)m * ldc + n], acc[i][j][rg]);
            }
        }
}

// split-K epilogue: [bias] + act + bf16 store. ACT: 0=none, 1=relu, 3=tanh
template<int ACT, bool HASB>
__global__ void sk_ep(const float* __restrict__ Cf, const float* __restrict__ bias,
                      u16* __restrict__ outp, int Ncols, int total4) {
    int t = blockIdx.x * 256 + threadIdx.x;
    if (t >= total4) return;
    int i = t << 2;
    float4 v = *(const float4*)(Cf + i);
    if (HASB) {
        int col = i & (Ncols - 1);
        v.x += bias[col]; v.y += bias[col + 1]; v.z += bias[col + 2]; v.w += bias[col + 3];
    }
    if (ACT == 1) { v.x = fmaxf(v.x, 0.f); v.y = fmaxf(v.y, 0.f);
                    v.z = fmaxf(v.z, 0.f); v.w = fmaxf(v.w, 0.f); }
    if (ACT == 3) { v.x = fast_tanh(v.x); v.y = fast_tanh(v.y);
                    v.z = fast_tanh(v.z); v.w = fast_tanh(v.w); }
    ushort4 o = { f2bf(v.x), f2bf(v.y), f2bf(v.z), f2bf(v.w) };
    *(ushort4*)(outp + i) = o;
}

// ---------------- gather-aggregate: agg[n][r*512+d] = sum_e vals[r][e] * x[col][d] ------
__device__ __forceinline__ void fma8(float* acc, uint4 u, float val) {
    acc[0] = fmaf(val, __uint_as_float(u.x << 16), acc[0]);
    acc[1] = fmaf(val, __uint_as_float(u.x & 0xffff0000u), acc[1]);
    acc[2] = fmaf(val, __uint_as_float(u.y << 16), acc[2]);
    acc[3] = fmaf(val, __uint_as_float(u.y & 0xffff0000u), acc[3]);
    acc[4] = fmaf(val, __uint_as_float(u.z << 16), acc[4]);
    acc[5] = fmaf(val, __uint_as_float(u.z & 0xffff0000u), acc[5]);
    acc[6] = fmaf(val, __uint_as_float(u.w << 16), acc[6]);
    acc[7] = fmaf(val, __uint_as_float(u.w & 0xffff0000u), acc[7]);
}

__global__ __launch_bounds__(256)
void spmm_agg(const u16* __restrict__ x, const int* __restrict__ offs,
              const int* __restrict__ colS, const float* __restrict__ valS,
              u16* __restrict__ agg)
{
    const int wave = threadIdx.x >> 6, lane = threadIdx.x & 63;
    const int n = blockIdx.x * 4 + wave;
    if (n >= NNODES) return;
    const u16* xr = x + (lane << 3);
    #pragma unroll
    for (int r = 0; r < RREL; ++r) {
        int s = offs[r * (NNODES + 1) + n];
        const int e = offs[r * (NNODES + 1) + n + 1];
        const int*   cp = colS + (size_t)r * EEDGES;
        const float* vp = valS + (size_t)r * EEDGES;
        float acc[8] = {0.f, 0.f, 0.f, 0.f, 0.f, 0.f, 0.f, 0.f};
        for (; s + 4 <= e; s += 4) {       // 4 gathers in flight
            int   c0 = cp[s], c1 = cp[s + 1], c2 = cp[s + 2], c3 = cp[s + 3];
            float v0 = vp[s], v1 = vp[s + 1], v2 = vp[s + 2], v3 = vp[s + 3];
            uint4 u0 = *(const uint4*)(xr + (size_t)c0 * DDIM);
            uint4 u1 = *(const uint4*)(xr + (size_t)c1 * DDIM);
            uint4 u2 = *(const uint4*)(xr + (size_t)c2 * DDIM);
            uint4 u3 = *(const uint4*)(xr + (size_t)c3 * DDIM);
            fma8(acc, u0, v0); fma8(acc, u1, v1); fma8(acc, u2, v2); fma8(acc, u3, v3);
        }
        for (; s < e; ++s) {
            int col = cp[s];
            float val = vp[s];
            uint4 u = *(const uint4*)(xr + (size_t)col * DDIM);
            fma8(acc, u, val);
        }
        uint4 o;
        o.x = (uint32_t)f2bf(acc[0]) | ((uint32_t)f2bf(acc[1]) << 16);
        o.y = (uint32_t)f2bf(acc[2]) | ((uint32_t)f2bf(acc[3]) << 16);
        o.z = (uint32_t)f2bf(acc[4]) | ((uint32_t)f2bf(acc[5]) << 16);
        o.w = (uint32_t)f2bf(acc[6]) | ((uint32_t)f2bf(acc[7]) << 16);
        *(uint4*)(agg + (size_t)n * XLW + (r << 9) + (lane << 3)) = o;
    }
}

// ---------------- frame_node gather (bf16 emb -> fp32 out) ----------------
__global__ void frame_gather(const u16* __restrict__ emb, const int* __restrict__ frame_list,
                             const int* __restrict__ gold, float* __restrict__ out) {
    int t = blockIdx.x * 256 + threadIdx.x;   // 32*64
    if (t >= 32 * 64) return;
    int b = t >> 6, lane = t & 63;
    int label = frame_list[b * 16 + gold[b]];
    const u16* src = emb + (size_t)label * DDIM + (lane << 3);
    float* dst = out + (size_t)b * OUTC + FRAMES + (lane << 3);
    float4 o0 = { bf2f(src[0]), bf2f(src[1]), bf2f(src[2]), bf2f(src[3]) };
    float4 o1 = { bf2f(src[4]), bf2f(src[5]), bf2f(src[6]), bf2f(src[7]) };
    *(float4*)(dst) = o0;
    *(float4*)(dst + 4) = o1;
}

extern "C" void kernel_launch(void* const* d_in, const int* in_sizes, int n_in,
                              void* d_out, int out_size, void* d_ws, size_t ws_size,
                              hipStream_t stream) {
    const float* target_span = (const float*)d_in[0];
    const float* frame_emb   = (const float*)d_in[1];
    const float* role_emb    = (const float*)d_in[2];
    const float* rel_W0      = (const float*)d_in[3];
    const float* rel_W1      = (const float*)d_in[4];
    const float* span_W1     = (const float*)d_in[5];
    const float* span_b1     = (const float*)d_in[6];
    const float* span_W2     = (const float*)d_in[7];
    const float* span_b2     = (const float*)d_in[8];
    const float* fp_W1       = (const float*)d_in[9];
    const float* fp_b1       = (const float*)d_in[10];
    const float* fp_W2       = (const float*)d_in[11];
    const float* fp_b2       = (const float*)d_in[12];
    const float* adj_vals    = (const float*)d_in[13];
    const int* fe_ids      = (const int*)d_in[14];
    const int* adj_rows    = (const int*)d_in[15];
    const int* adj_cols    = (const int*)d_in[16];
    const int* gold_id     = (const int*)d_in[17];
    const int* frame_list  = (const int*)d_in[18];
    float* out = (float*)d_out;

    char* ws = (char*)d_ws;
    size_t off = 0;
    auto take = [&](size_t bytes) -> char* {
        char* p = ws + off;
        off = (off + bytes + 255) & ~(size_t)255;
        return p;
    };
    u16* x      = (u16*)take((size_t)MPAD * DDIM * 2);
    u16* agg    = (u16*)take((size_t)MPAD * XLW * 2);
    float* C32  = (float*)take((size_t)MPAD * DDIM * 4);
    u16* w0t    = (u16*)take((size_t)512 * XLW * 2);     // Wcat0^T: [512 n][2560 k]
    u16* w1t    = (u16*)take((size_t)512 * XLW * 2);
    u16* s1t    = (u16*)take((size_t)2048 * 2048 * 2);
    u16* s2t    = (u16*)take((size_t)512 * 2048 * 2);
    u16* f1t    = (u16*)take((size_t)512 * 512 * 2);
    u16* f2t    = (u16*)take((size_t)512 * 512 * 2);
    int* counts = (int*)take((size_t)RREL * NNODES * 4);
    int* offs   = (int*)take((size_t)RREL * (NNODES + 1) * 4);
    int* cursor = (int*)take((size_t)RREL * NNODES * 4);
    int* colS   = (int*)take((size_t)RREL * EEDGES * 4);
    float* valS = (float*)take((size_t)RREL * EEDGES * 4);
    u16* tsp    = (u16*)take((size_t)128 * 2048 * 2);
    u16* h1     = (u16*)take((size_t)128 * 2048 * 2);
    u16* tn     = (u16*)take((size_t)128 * 512 * 2);
    u16* h2     = (u16*)take((size_t)128 * 512 * 2);
    u16* Qb     = (u16*)take((size_t)128 * 512 * 2);
    float* CfAll = (float*)take((size_t)(128 * 2048 + 3 * 128 * 512) * 4);
    float* Cf1 = CfAll;
    float* Cf2 = Cf1 + 128 * 2048;
    float* Cf3 = Cf2 + 128 * 512;
    float* Cf4 = Cf3 + 128 * 512;

    hipMemsetAsync(counts, 0, (size_t)RREL * NNODES * 4, stream);
    hipMemsetAsync(C32, 0, (size_t)MPAD * DDIM * 4, stream);
    hipMemsetAsync(CfAll, 0, (size_t)(128 * 2048 + 3 * 128 * 512) * 4, stream);
    hipMemsetAsync(out, 0, (size_t)32 * OUTC * 4, stream);

    // CSR build (shared by both layers)
    hist_k<<<(RREL * EEDGES + 255) / 256, 256, 0, stream>>>(adj_rows, counts);
    scan_offsets<<<RREL, 1024, 0, stream>>>(counts, offs, cursor);
    scatter_k<<<(RREL * EEDGES + 255) / 256, 256, 0, stream>>>(adj_rows, adj_cols, adj_vals,
                                                               cursor, colS, valS);
    // inputs (fp32 -> bf16): x assembly + tsp pad, one dispatch
    prep_inputs<<<BX_BLOCKS + 256, 256, 0, stream>>>(frame_emb, role_emb, fe_ids,
                                                     target_span, x, tsp);
    // all weight transposes, one dispatch
    transpose_all<<<8192, 256, 0, stream>>>(rel_W0, rel_W1, span_W1, span_W2, fp_W1, fp_W2,
                                            w0t, w1t, s1t, s2t, f1t, f2t);

    // relGCN layer 1: gather-agg -> split-K(z=5, per relation) GEMM -> tanh epilogue
    spmm_agg<<<(NNODES + 3) / 4, 256, 0, stream>>>(x, offs, colS, valS, agg);
    gemm_sk<false><<<dim3(4, MPAD / 128, 5), 256, 0, stream>>>(
        agg, w0t, C32, XLW, 512, XLW, XLW, 512, MPAD);
    sk_ep<3, false><<<(MPAD * 512 / 4 + 255) / 256, 256, 0, stream>>>(
        C32, nullptr, x, 512, MPAD * 512 / 4);
    hipMemsetAsync(C32, 0, (size_t)MPAD * DDIM * 4, stream);
    // relGCN layer 2
    spmm_agg<<<(NNODES + 3) / 4, 256, 0, stream>>>(x, offs, colS, valS, agg);
    gemm_sk<false><<<dim3(4, MPAD / 128, 5), 256, 0, stream>>>(
        agg, w1t, C32, XLW, 512, XLW, XLW, 512, MPAD);
    sk_ep<3, false><<<(MPAD * 512 / 4 + 255) / 256, 256, 0, stream>>>(
        C32, nullptr, x, 512, MPAD * 512 / 4);

    // span MLP chain via split-K + epilogues
    gemm_sk<false><<<dim3(16, 1, 8), 256, 0, stream>>>(tsp, s1t, Cf1, 2048, 256, 2048, 2048, 2048, 128);
    sk_ep<1, true><<<(128 * 2048 / 4 + 255) / 256, 256, 0, stream>>>(Cf1, span_b1, h1, 2048, 128 * 2048 / 4);
    gemm_sk<false><<<dim3(4, 1, 8), 256, 0, stream>>>(h1, s2t, Cf2, 2048, 256, 2048, 2048, 512, 128);
    sk_ep<0, true><<<(128 * 512 / 4 + 255) / 256, 256, 0, stream>>>(Cf2, span_b2, tn, 512, 128 * 512 / 4);
    gemm_sk<false><<<dim3(4, 1, 4), 256, 0, stream>>>(tn, f1t, Cf3, 512, 128, 512, 512, 512, 128);
    sk_ep<1, true><<<(128 * 512 / 4 + 255) / 256, 256, 0, stream>>>(Cf3, fp_b1, h2, 512, 128 * 512 / 4);
    gemm_sk<false><<<dim3(4, 1, 4), 256, 0, stream>>>(h2, f2t, Cf4, 512, 128, 512, 512, 512, 128);
    sk_ep<3, true><<<(128 * 512 / 4 + 255) / 256, 256, 0, stream>>>(Cf4, fp_b2, Qb, 512, 128 * 512 / 4);

    // pred_frame_weight = Q @ emb^T, atomics straight into fp32 out[:, :1200]
    // (cols 1200..1279 get garbage adds, overwritten by frame_gather below)
    gemm_sk<true><<<dim3((FRAMES + 127) / 128, 1, 4), 256, 0, stream>>>(
        Qb, x, out, 512, 128, 512, 512, OUTC, 32);
    // frame_node gather; writes out[:, 1200:1712] as fp32
    frame_gather<<<8, 256, 0, stream>>>(x, frame_list, gold_id, out);
}

// Round 5
// 542.803 us; speedup vs baseline: 1.1576x; 1.1576x over previous
//
#include <hip/hip_runtime.h>
#include <hip/hip_bf16.h>
#include <stdint.h>

typedef unsigned short u16;
typedef __attribute__((ext_vector_type(8))) short short8;
typedef __attribute__((ext_vector_type(4))) float float4v;

#define NNODES 11201
#define MPAD   11264
#define EEDGES 100000
#define RREL   5
#define DDIM   512
#define XLW    2560      // RREL*DDIM
#define FRAMES 1200
#define OUTC   1712      // FRAMES + DDIM

__device__ __forceinline__ float bf2f(u16 h) {
    return __uint_as_float(((uint32_t)h) << 16);
}
__device__ __forceinline__ u16 f2bf(float f) {
    uint32_t x = __float_as_uint(f);
    x += 0x7fffu + ((x >> 16) & 1u);   // RNE
    return (u16)(x >> 16);
}
__device__ __forceinline__ float fast_tanh(float v) {
    v = fminf(fmaxf(v, -10.f), 10.f);
    float ex = __expf(2.f * v);
    return (ex - 1.f) / (ex + 1.f);
}

// ---------------- CSR build ----------------
__global__ void hist_k(const int* __restrict__ rows, int* __restrict__ counts) {
    int tid = blockIdx.x * 256 + threadIdx.x;
    if (tid >= RREL * EEDGES) return;
    int r = tid / EEDGES;
    atomicAdd(&counts[r * NNODES + rows[tid]], 1);
}

// single-pass scan: 1024 threads, 11 elems/thread; writes offs AND cursor
__global__ __launch_bounds__(1024) void scan_offsets(const int* __restrict__ counts,
                                                     int* __restrict__ offs,
                                                     int* __restrict__ cursor) {
    const int PER = 11;          // 1024*11 = 11264 >= NNODES
    int r = blockIdx.x;
    const int* c = counts + (size_t)r * NNODES;
    int* o = offs + (size_t)r * (NNODES + 1);
    int* cur = cursor + (size_t)r * NNODES;
    __shared__ int wsum[16];
    const int lane = threadIdx.x & 63, wid = threadIdx.x >> 6;
    int base = threadIdx.x * PER;
    int v[PER];
    int s = 0;
    #pragma unroll
    for (int t = 0; t < PER; ++t) {
        int idx = base + t;
        v[t] = (idx < NNODES) ? c[idx] : 0;
        s += v[t];
    }
    int incl = s;
    #pragma unroll
    for (int d = 1; d < 64; d <<= 1) {
        int t = __shfl_up(incl, d, 64);
        if (lane >= d) incl += t;
    }
    if (lane == 63) wsum[wid] = incl;
    __syncthreads();
    if (wid == 0) {
        int wv = (lane < 16) ? wsum[lane] : 0;
        #pragma unroll
        for (int d = 1; d < 16; d <<= 1) {
            int t = __shfl_up(wv, d, 64);
            if (lane >= d) wv += t;
        }
        if (lane < 16) wsum[lane] = wv;
    }
    __syncthreads();
    int run = incl - s + ((wid > 0) ? wsum[wid - 1] : 0);   // exclusive prefix
    #pragma unroll
    for (int t = 0; t < PER; ++t) {
        int idx = base + t;
        if (idx < NNODES) { o[idx] = run; cur[idx] = run; }
        run += v[t];
    }
    if (threadIdx.x == 1023) o[NNODES] = run;
}

__global__ void scatter_k(const int* __restrict__ rows, const int* __restrict__ cols,
                          const float* __restrict__ vals, int* __restrict__ cursor,
                          int* __restrict__ colS, float* __restrict__ valS) {
    int tid = blockIdx.x * 256 + threadIdx.x;
    if (tid >= RREL * EEDGES) return;
    int r = tid / EEDGES;
    int row = rows[tid];
    int pos = atomicAdd(&cursor[r * NNODES + row], 1);
    colS[(size_t)r * EEDGES + pos] = cols[tid];
    valS[(size_t)r * EEDGES + pos] = vals[tid];
}

// ---------------- input assembly: build_x (fp32->bf16 gather) + tsp pad, one dispatch ----
#define BX_BLOCKS 5601     // ceil(NNODES*128/256)
__global__ void prep_inputs(const float* __restrict__ frame_emb,
                            const float* __restrict__ role_emb,
                            const int* __restrict__ fe_ids,
                            const float* __restrict__ ts,
                            u16* __restrict__ x, u16* __restrict__ tsp) {
    int bid = blockIdx.x;
    if (bid < BX_BLOCKS) {
        int t = bid * 256 + threadIdx.x;
        int row = t >> 7, c4 = (t & 127) << 2;
        if (row >= NNODES) return;
        const float* src = (row < FRAMES) ? (frame_emb + (size_t)row * DDIM)
                                          : (role_emb + (size_t)fe_ids[row - FRAMES] * DDIM);
        float4 v = *(const float4*)(src + c4);
        ushort4 o = { f2bf(v.x), f2bf(v.y), f2bf(v.z), f2bf(v.w) };
        *(ushort4*)(x + (size_t)row * DDIM + c4) = o;
    } else {
        int t = (bid - BX_BLOCKS) * 256 + threadIdx.x;   // < 65536
        int row = t >> 9, c4 = (t & 511) << 2;
        ushort4 o = {0, 0, 0, 0};
        if (row < 32) {
            float4 v = *(const float4*)(ts + (size_t)row * 2048 + c4);
            o = ushort4{ f2bf(v.x), f2bf(v.y), f2bf(v.z), f2bf(v.w) };
        }
        *(ushort4*)(tsp + (size_t)row * 2048 + c4) = o;
    }
}

// ---------------- all 6 weight transposes (fp32 -> bf16) in one dispatch ---------------
__global__ void transpose_all(const float* __restrict__ w0, const float* __restrict__ w1,
                              const float* __restrict__ s1, const float* __restrict__ s2,
                              const float* __restrict__ f1, const float* __restrict__ f2,
                              u16* __restrict__ w0t, u16* __restrict__ w1t,
                              u16* __restrict__ s1t, u16* __restrict__ s2t,
                              u16* __restrict__ f1t, u16* __restrict__ f2t) {
    int b = blockIdx.x;
    const float* src; u16* dst;
    int cols, ldOut, bx, by;
    size_t zcol = 0;
    if (b < 1280) {
        int rel = b >> 8, rem = b & 255;
        src = w0 + (size_t)rel * 262144; dst = w0t;
        cols = 512; ldOut = XLW; zcol = (size_t)rel * 512;
        bx = rem & 15; by = rem >> 4;
    } else if (b < 2560) {
        b -= 1280;
        int rel = b >> 8, rem = b & 255;
        src = w1 + (size_t)rel * 262144; dst = w1t;
        cols = 512; ldOut = XLW; zcol = (size_t)rel * 512;
        bx = rem & 15; by = rem >> 4;
    } else if (b < 6656) {
        b -= 2560;
        src = s1; dst = s1t; cols = 2048; ldOut = 2048;
        bx = b & 63; by = b >> 6;
    } else if (b < 7680) {
        b -= 6656;
        src = s2; dst = s2t; cols = 512; ldOut = 2048;
        bx = b & 15; by = b >> 4;
    } else if (b < 7936) {
        b -= 7680;
        src = f1; dst = f1t; cols = 512; ldOut = 512;
        bx = b & 15; by = b >> 4;
    } else {
        b -= 7936;
        src = f2; dst = f2t; cols = 512; ldOut = 512;
        bx = b & 15; by = b >> 4;
    }
    __shared__ u16 tile[32][33];
    int c0 = bx * 32, r0 = by * 32;
    int tx = threadIdx.x & 31, ty = threadIdx.x >> 5;   // 256 threads
    #pragma unroll
    for (int i = 0; i < 4; ++i) {
        int rr = ty + i * 8;
        tile[rr][tx] = f2bf(src[(size_t)(r0 + rr) * cols + c0 + tx]);
    }
    __syncthreads();
    #pragma unroll
    for (int i = 0; i < 4; ++i) {
        int rr = ty + i * 8;
        dst[(size_t)(c0 + rr) * ldOut + zcol + r0 + tx] = tile[tx][rr];
    }
}

// ------- unified BT-GEMM, double-buffered LDS staging ------------------------------------
// C[m][n] (+)= sum_{k in z-chunk} A[m][k] * Bt[n][k]
// EPI: 0 none, 1 bias+relu, 2 bias, 3 bias+tanh, 4 tanh.
// ATOMIC: fp32 atomicAdd into Cv (EPI ignored). FOUT: fp32 direct store. GUARDS: m/n guards.
template<int EPI, bool FOUT, bool ATOMIC, bool GUARDS>
__global__ __launch_bounds__(256)
void gemm_u(const u16* __restrict__ A, const u16* __restrict__ Bt,
            void* __restrict__ Cv, const float* __restrict__ bias,
            int Kc, int lda, int ldb, int ldc, int mGuard, int nGuard)
{
    __shared__ u16 As[2][128 * 32];
    __shared__ u16 Bs[2][128 * 32];
    const int tid = threadIdx.x;
    const int wave = tid >> 6, lane = tid & 63;
    const int m0 = blockIdx.y * 128, n0 = blockIdx.x * 128;
    const int kb = blockIdx.z * Kc;
    const int srow = lane >> 2;            // 16 rows per 1KB wave-stage
    const int skoff = (lane & 3) << 3;     // 4 chunks of 8 bf16
    const int fr = lane & 15, quad = lane >> 4;
    const int wm = (wave & 1) << 6, wn = (wave >> 1) << 6;
    float4v acc[4][4] = {};

    const u16* Abase = A  + (size_t)(m0 + srow) * lda + skoff;
    const u16* Bbase = Bt + (size_t)(n0 + srow) * ldb + skoff;

    auto stage = [&](int buf, int k0) {
        #pragma unroll
        for (int i = 0; i < 2; ++i) {
            const int rb = (wave + i * 4) << 4;   // 0,16,...,112
            __builtin_amdgcn_global_load_lds(
                (const __attribute__((address_space(1))) unsigned int*)(Abase + (size_t)rb * lda + k0),
                (__attribute__((address_space(3))) unsigned int*)(&As[buf][rb * 32]), 16, 0, 0);
            __builtin_amdgcn_global_load_lds(
                (const __attribute__((address_space(1))) unsigned int*)(Bbase + (size_t)rb * ldb + k0),
                (__attribute__((address_space(3))) unsigned int*)(&Bs[buf][rb * 32]), 16, 0, 0);
        }
    };
    auto compute = [&](int buf) {
        short8 a[4], b[4];
        #pragma unroll
        for (int t = 0; t < 4; ++t)
            a[t] = *(const short8*)(&As[buf][((wm + t * 16 + fr) << 5) + (quad << 3)]);
        #pragma unroll
        for (int t = 0; t < 4; ++t)
            b[t] = *(const short8*)(&Bs[buf][((wn + t * 16 + fr) << 5) + (quad << 3)]);
        #pragma unroll
        for (int i = 0; i < 4; ++i)
            #pragma unroll
            for (int j = 0; j < 4; ++j)
                acc[i][j] = __builtin_amdgcn_mfma_f32_16x16x32_bf16(a[i], b[j], acc[i][j], 0, 0, 0);
    };

    // dbuf pipeline: stage k+1 in flight while computing k; single barrier per iter.
    stage(0, kb);
    __syncthreads();
    int cur = 0;
    for (int k0 = kb + 32; k0 < kb + Kc; k0 += 32) {
        stage(cur ^ 1, k0);    // DMA overlaps compute below
        compute(cur);
        __syncthreads();       // drains next stage + all ds_reads of cur
        cur ^= 1;
    }
    compute(cur);

    #pragma unroll
    for (int i = 0; i < 4; ++i) {
        #pragma unroll
        for (int j = 0; j < 4; ++j) {
            const int n = n0 + wn + j * 16 + fr;
            float bv = 0.f;
            if ((EPI == 1 || EPI == 2 || EPI == 3) && (!GUARDS || n < nGuard)) bv = bias[n];
            #pragma unroll
            for (int rg = 0; rg < 4; ++rg) {
                const int m = m0 + wm + i * 16 + (quad << 2) + rg;
                if (GUARDS && (m >= mGuard || n >= nGuard)) continue;
                float v = acc[i][j][rg];
                if (ATOMIC) {
                    atomicAdd((float*)Cv + (size_t)m * ldc + n, v);
                } else {
                    if (EPI == 1 || EPI == 2 || EPI == 3) v += bv;
                    if (EPI == 1) v = fmaxf(v, 0.f);
                    if (EPI == 3 || EPI == 4) v = fast_tanh(v);
                    if (FOUT) ((float*)Cv)[(size_t)m * ldc + n] = v;
                    else      ((u16*)Cv)[(size_t)m * ldc + n] = f2bf(v);
                }
            }
        }
    }
}

// split-K epilogue: [bias] + act + bf16 store. ACT: 0=none, 1=relu, 3=tanh
template<int ACT, bool HASB>
__global__ void sk_ep(const float* __restrict__ Cf, const float* __restrict__ bias,
                      u16* __restrict__ outp, int Ncols, int total4) {
    int t = blockIdx.x * 256 + threadIdx.x;
    if (t >= total4) return;
    int i = t << 2;
    float4 v = *(const float4*)(Cf + i);
    if (HASB) {
        int col = i & (Ncols - 1);
        v.x += bias[col]; v.y += bias[col + 1]; v.z += bias[col + 2]; v.w += bias[col + 3];
    }
    if (ACT == 1) { v.x = fmaxf(v.x, 0.f); v.y = fmaxf(v.y, 0.f);
                    v.z = fmaxf(v.z, 0.f); v.w = fmaxf(v.w, 0.f); }
    if (ACT == 3) { v.x = fast_tanh(v.x); v.y = fast_tanh(v.y);
                    v.z = fast_tanh(v.z); v.w = fast_tanh(v.w); }
    ushort4 o = { f2bf(v.x), f2bf(v.y), f2bf(v.z), f2bf(v.w) };
    *(ushort4*)(outp + i) = o;
}

// ---------------- gather-aggregate: agg[n][r*512+d] = sum_e vals[r][e] * x[col][d] ------
__device__ __forceinline__ void fma8(float* acc, uint4 u, float val) {
    acc[0] = fmaf(val, __uint_as_float(u.x << 16), acc[0]);
    acc[1] = fmaf(val, __uint_as_float(u.x & 0xffff0000u), acc[1]);
    acc[2] = fmaf(val, __uint_as_float(u.y << 16), acc[2]);
    acc[3] = fmaf(val, __uint_as_float(u.y & 0xffff0000u), acc[3]);
    acc[4] = fmaf(val, __uint_as_float(u.z << 16), acc[4]);
    acc[5] = fmaf(val, __uint_as_float(u.z & 0xffff0000u), acc[5]);
    acc[6] = fmaf(val, __uint_as_float(u.w << 16), acc[6]);
    acc[7] = fmaf(val, __uint_as_float(u.w & 0xffff0000u), acc[7]);
}

__global__ __launch_bounds__(256)
void spmm_agg(const u16* __restrict__ x, const int* __restrict__ offs,
              const int* __restrict__ colS, const float* __restrict__ valS,
              u16* __restrict__ agg)
{
    const int wave = threadIdx.x >> 6, lane = threadIdx.x & 63;
    const int n = blockIdx.x * 4 + wave;
    if (n >= NNODES) return;
    const u16* xr = x + (lane << 3);
    #pragma unroll
    for (int r = 0; r < RREL; ++r) {
        int s = offs[r * (NNODES + 1) + n];
        const int e = offs[r * (NNODES + 1) + n + 1];
        const int*   cp = colS + (size_t)r * EEDGES;
        const float* vp = valS + (size_t)r * EEDGES;
        float acc[8] = {0.f, 0.f, 0.f, 0.f, 0.f, 0.f, 0.f, 0.f};
        while (s < e) {                    // depth-8 batches, wave-uniform guards
            int m = e - s; if (m > 8) m = 8;
            int   ct[8]; float vt[8]; uint4 u[8];
            #pragma unroll
            for (int t = 0; t < 8; ++t)
                if (t < m) { ct[t] = cp[s + t]; vt[t] = vp[s + t]; }
            #pragma unroll
            for (int t = 0; t < 8; ++t)
                if (t < m) u[t] = *(const uint4*)(xr + (size_t)ct[t] * DDIM);
            #pragma unroll
            for (int t = 0; t < 8; ++t)
                if (t < m) fma8(acc, u[t], vt[t]);
            s += 8;
        }
        uint4 o;
        o.x = (uint32_t)f2bf(acc[0]) | ((uint32_t)f2bf(acc[1]) << 16);
        o.y = (uint32_t)f2bf(acc[2]) | ((uint32_t)f2bf(acc[3]) << 16);
        o.z = (uint32_t)f2bf(acc[4]) | ((uint32_t)f2bf(acc[5]) << 16);
        o.w = (uint32_t)f2bf(acc[6]) | ((uint32_t)f2bf(acc[7]) << 16);
        *(uint4*)(agg + (size_t)n * XLW + (r << 9) + (lane << 3)) = o;
    }
}

// ---------------- frame_node gather (bf16 emb -> fp32 out) ----------------
__global__ void frame_gather(const u16* __restrict__ emb, const int* __restrict__ frame_list,
                             const int* __restrict__ gold, float* __restrict__ out) {
    int t = blockIdx.x * 256 + threadIdx.x;   // 32*64
    if (t >= 32 * 64) return;
    int b = t >> 6, lane = t & 63;
    int label = frame_list[b * 16 + gold[b]];
    const u16* src = emb + (size_t)label * DDIM + (lane << 3);
    float* dst = out + (size_t)b * OUTC + FRAMES + (lane << 3);
    float4 o0 = { bf2f(src[0]), bf2f(src[1]), bf2f(src[2]), bf2f(src[3]) };
    float4 o1 = { bf2f(src[4]), bf2f(src[5]), bf2f(src[6]), bf2f(src[7]) };
    *(float4*)(dst) = o0;
    *(float4*)(dst + 4) = o1;
}

extern "C" void kernel_launch(void* const* d_in, const int* in_sizes, int n_in,
                              void* d_out, int out_size, void* d_ws, size_t ws_size,
                              hipStream_t stream) {
    const float* target_span = (const float*)d_in[0];
    const float* frame_emb   = (const float*)d_in[1];
    const float* role_emb    = (const float*)d_in[2];
    const float* rel_W0      = (const float*)d_in[3];
    const float* rel_W1      = (const float*)d_in[4];
    const float* span_W1     = (const float*)d_in[5];
    const float* span_b1     = (const float*)d_in[6];
    const float* span_W2     = (const float*)d_in[7];
    const float* span_b2     = (const float*)d_in[8];
    const float* fp_W1       = (const float*)d_in[9];
    const float* fp_b1       = (const float*)d_in[10];
    const float* fp_W2       = (const float*)d_in[11];
    const float* fp_b2       = (const float*)d_in[12];
    const float* adj_vals    = (const float*)d_in[13];
    const int* fe_ids      = (const int*)d_in[14];
    const int* adj_rows    = (const int*)d_in[15];
    const int* adj_cols    = (const int*)d_in[16];
    const int* gold_id     = (const int*)d_in[17];
    const int* frame_list  = (const int*)d_in[18];
    float* out = (float*)d_out;

    char* ws = (char*)d_ws;
    size_t off = 0;
    auto take = [&](size_t bytes) -> char* {
        char* p = ws + off;
        off = (off + bytes + 255) & ~(size_t)255;
        return p;
    };
    u16* x      = (u16*)take((size_t)MPAD * DDIM * 2);
    u16* agg    = (u16*)take((size_t)MPAD * XLW * 2);
    u16* w0t    = (u16*)take((size_t)512 * XLW * 2);     // Wcat0^T: [512 n][2560 k]
    u16* w1t    = (u16*)take((size_t)512 * XLW * 2);
    u16* s1t    = (u16*)take((size_t)2048 * 2048 * 2);
    u16* s2t    = (u16*)take((size_t)512 * 2048 * 2);
    u16* f1t    = (u16*)take((size_t)512 * 512 * 2);
    u16* f2t    = (u16*)take((size_t)512 * 512 * 2);
    int* counts = (int*)take((size_t)RREL * NNODES * 4);
    int* offs   = (int*)take((size_t)RREL * (NNODES + 1) * 4);
    int* cursor = (int*)take((size_t)RREL * NNODES * 4);
    int* colS   = (int*)take((size_t)RREL * EEDGES * 4);
    float* valS = (float*)take((size_t)RREL * EEDGES * 4);
    u16* tsp    = (u16*)take((size_t)128 * 2048 * 2);
    u16* h1     = (u16*)take((size_t)128 * 2048 * 2);
    u16* tn     = (u16*)take((size_t)128 * 512 * 2);
    u16* h2     = (u16*)take((size_t)128 * 512 * 2);
    u16* Qb     = (u16*)take((size_t)128 * 512 * 2);
    float* CfAll = (float*)take((size_t)(128 * 2048 + 3 * 128 * 512) * 4);
    float* Cf1 = CfAll;
    float* Cf2 = Cf1 + 128 * 2048;
    float* Cf3 = Cf2 + 128 * 512;
    float* Cf4 = Cf3 + 128 * 512;

    hipMemsetAsync(counts, 0, (size_t)RREL * NNODES * 4, stream);
    hipMemsetAsync(CfAll, 0, (size_t)(128 * 2048 + 3 * 128 * 512) * 4, stream);

    // CSR build (shared by both layers)
    hist_k<<<(RREL * EEDGES + 255) / 256, 256, 0, stream>>>(adj_rows, counts);
    scan_offsets<<<RREL, 1024, 0, stream>>>(counts, offs, cursor);
    scatter_k<<<(RREL * EEDGES + 255) / 256, 256, 0, stream>>>(adj_rows, adj_cols, adj_vals,
                                                               cursor, colS, valS);
    // inputs (fp32 -> bf16): x assembly + tsp pad, one dispatch
    prep_inputs<<<BX_BLOCKS + 256, 256, 0, stream>>>(frame_emb, role_emb, fe_ids,
                                                     target_span, x, tsp);
    // all weight transposes, one dispatch
    transpose_all<<<8192, 256, 0, stream>>>(rel_W0, rel_W1, span_W1, span_W2, fp_W1, fp_W2,
                                            w0t, w1t, s1t, s2t, f1t, f2t);

    // relGCN layer 1: gather-agg -> dbuf GEMM (K=2560) with fused tanh, direct bf16 store
    spmm_agg<<<(NNODES + 3) / 4, 256, 0, stream>>>(x, offs, colS, valS, agg);
    gemm_u<4, false, false, true><<<dim3(4, MPAD / 128, 1), 256, 0, stream>>>(
        agg, w0t, x, nullptr, XLW, XLW, XLW, 512, NNODES, 512);
    // relGCN layer 2
    spmm_agg<<<(NNODES + 3) / 4, 256, 0, stream>>>(x, offs, colS, valS, agg);
    gemm_u<4, false, false, true><<<dim3(4, MPAD / 128, 1), 256, 0, stream>>>(
        agg, w1t, x, nullptr, XLW, XLW, XLW, 512, NNODES, 512);

    // span MLP chain via split-K (small C, atomics cheap) + epilogues
    gemm_u<0, false, true, false><<<dim3(16, 1, 8), 256, 0, stream>>>(
        tsp, s1t, Cf1, nullptr, 256, 2048, 2048, 2048, 128, 2048);
    sk_ep<1, true><<<(128 * 2048 / 4 + 255) / 256, 256, 0, stream>>>(Cf1, span_b1, h1, 2048, 128 * 2048 / 4);
    gemm_u<0, false, true, false><<<dim3(4, 1, 8), 256, 0, stream>>>(
        h1, s2t, Cf2, nullptr, 256, 2048, 2048, 512, 128, 512);
    sk_ep<0, true><<<(128 * 512 / 4 + 255) / 256, 256, 0, stream>>>(Cf2, span_b2, tn, 512, 128 * 512 / 4);
    gemm_u<0, false, true, false><<<dim3(4, 1, 4), 256, 0, stream>>>(
        tn, f1t, Cf3, nullptr, 128, 512, 512, 512, 128, 512);
    sk_ep<1, true><<<(128 * 512 / 4 + 255) / 256, 256, 0, stream>>>(Cf3, fp_b1, h2, 512, 128 * 512 / 4);
    gemm_u<0, false, true, false><<<dim3(4, 1, 4), 256, 0, stream>>>(
        h2, f2t, Cf4, nullptr, 128, 512, 512, 512, 128, 512);
    sk_ep<3, true><<<(128 * 512 / 4 + 255) / 256, 256, 0, stream>>>(Cf4, fp_b2, Qb, 512, 128 * 512 / 4);

    // pred_frame_weight = Q @ emb^T: direct fp32 store into out[:, :1200] (m<32, n<1200)
    gemm_u<0, true, false, true><<<dim3(10, 1, 1), 256, 0, stream>>>(
        Qb, x, out, nullptr, 512, 512, 512, OUTC, 32, FRAMES);
    // frame_node gather; writes out[:, 1200:1712] as fp32
    frame_gather<<<8, 256, 0, stream>>>(x, frame_list, gold_id, out);
}

// Round 6
// 533.051 us; speedup vs baseline: 1.1788x; 1.0183x over previous
//
#include <hip/hip_runtime.h>
#include <hip/hip_bf16.h>
#include <stdint.h>

typedef unsigned short u16;
typedef __attribute__((ext_vector_type(8))) short short8;
typedef __attribute__((ext_vector_type(4))) float float4v;

#define NNODES 11201
#define MPAD   11264
#define EEDGES 100000
#define RREL   5
#define DDIM   512
#define XLW    2560      // RREL*DDIM
#define FRAMES 1200
#define OUTC   1712      // FRAMES + DDIM

__device__ __forceinline__ float bf2f(u16 h) {
    return __uint_as_float(((uint32_t)h) << 16);
}
__device__ __forceinline__ u16 f2bf(float f) {
    uint32_t x = __float_as_uint(f);
    x += 0x7fffu + ((x >> 16) & 1u);   // RNE
    return (u16)(x >> 16);
}
__device__ __forceinline__ float fast_tanh(float v) {
    v = fminf(fmaxf(v, -10.f), 10.f);
    float ex = __expf(2.f * v);
    return (ex - 1.f) / (ex + 1.f);
}

// ---------------- CSR build ----------------
__global__ void hist_k(const int* __restrict__ rows, int* __restrict__ counts) {
    int tid = blockIdx.x * 256 + threadIdx.x;
    if (tid >= RREL * EEDGES) return;
    int r = tid / EEDGES;
    atomicAdd(&counts[r * NNODES + rows[tid]], 1);
}

// single-pass scan: 1024 threads, 11 elems/thread; writes offs AND cursor
__global__ __launch_bounds__(1024) void scan_offsets(const int* __restrict__ counts,
                                                     int* __restrict__ offs,
                                                     int* __restrict__ cursor) {
    const int PER = 11;          // 1024*11 = 11264 >= NNODES
    int r = blockIdx.x;
    const int* c = counts + (size_t)r * NNODES;
    int* o = offs + (size_t)r * (NNODES + 1);
    int* cur = cursor + (size_t)r * NNODES;
    __shared__ int wsum[16];
    const int lane = threadIdx.x & 63, wid = threadIdx.x >> 6;
    int base = threadIdx.x * PER;
    int v[PER];
    int s = 0;
    #pragma unroll
    for (int t = 0; t < PER; ++t) {
        int idx = base + t;
        v[t] = (idx < NNODES) ? c[idx] : 0;
        s += v[t];
    }
    int incl = s;
    #pragma unroll
    for (int d = 1; d < 64; d <<= 1) {
        int t = __shfl_up(incl, d, 64);
        if (lane >= d) incl += t;
    }
    if (lane == 63) wsum[wid] = incl;
    __syncthreads();
    if (wid == 0) {
        int wv = (lane < 16) ? wsum[lane] : 0;
        #pragma unroll
        for (int d = 1; d < 16; d <<= 1) {
            int t = __shfl_up(wv, d, 64);
            if (lane >= d) wv += t;
        }
        if (lane < 16) wsum[lane] = wv;
    }
    __syncthreads();
    int run = incl - s + ((wid > 0) ? wsum[wid - 1] : 0);   // exclusive prefix
    #pragma unroll
    for (int t = 0; t < PER; ++t) {
        int idx = base + t;
        if (idx < NNODES) { o[idx] = run; cur[idx] = run; }
        run += v[t];
    }
    if (threadIdx.x == 1023) o[NNODES] = run;
}

__global__ void scatter_k(const int* __restrict__ rows, const int* __restrict__ cols,
                          const float* __restrict__ vals, int* __restrict__ cursor,
                          int* __restrict__ colS, float* __restrict__ valS) {
    int tid = blockIdx.x * 256 + threadIdx.x;
    if (tid >= RREL * EEDGES) return;
    int r = tid / EEDGES;
    int row = rows[tid];
    int pos = atomicAdd(&cursor[r * NNODES + row], 1);
    colS[(size_t)r * EEDGES + pos] = cols[tid];
    valS[(size_t)r * EEDGES + pos] = vals[tid];
}

// ------- merged prep: x assembly + tsp pad + all 6 weight transposes, one dispatch ------
#define BX_BLOCKS 5601                 // ceil(NNODES*128/256)
#define TSP_BLOCKS 256
#define TR_BASE (BX_BLOCKS + TSP_BLOCKS)
__global__ void prep_all(const float* __restrict__ frame_emb,
                         const float* __restrict__ role_emb,
                         const int* __restrict__ fe_ids,
                         const float* __restrict__ ts,
                         const float* __restrict__ w0, const float* __restrict__ w1,
                         const float* __restrict__ s1, const float* __restrict__ s2,
                         const float* __restrict__ f1, const float* __restrict__ f2,
                         u16* __restrict__ x, u16* __restrict__ tsp,
                         u16* __restrict__ w0t, u16* __restrict__ w1t,
                         u16* __restrict__ s1t, u16* __restrict__ s2t,
                         u16* __restrict__ f1t, u16* __restrict__ f2t) {
    int bid = blockIdx.x;
    if (bid < BX_BLOCKS) {
        int t = bid * 256 + threadIdx.x;
        int row = t >> 7, c4 = (t & 127) << 2;
        if (row >= NNODES) return;
        const float* src = (row < FRAMES) ? (frame_emb + (size_t)row * DDIM)
                                          : (role_emb + (size_t)fe_ids[row - FRAMES] * DDIM);
        float4 v = *(const float4*)(src + c4);
        ushort4 o = { f2bf(v.x), f2bf(v.y), f2bf(v.z), f2bf(v.w) };
        *(ushort4*)(x + (size_t)row * DDIM + c4) = o;
        return;
    }
    if (bid < TR_BASE) {
        int t = (bid - BX_BLOCKS) * 256 + threadIdx.x;   // < 65536
        int row = t >> 9, c4 = (t & 511) << 2;
        ushort4 o = {0, 0, 0, 0};
        if (row < 32) {
            float4 v = *(const float4*)(ts + (size_t)row * 2048 + c4);
            o = ushort4{ f2bf(v.x), f2bf(v.y), f2bf(v.z), f2bf(v.w) };
        }
        *(ushort4*)(tsp + (size_t)row * 2048 + c4) = o;
        return;
    }
    int b = bid - TR_BASE;
    const float* src; u16* dst;
    int cols, ldOut, bx, by;
    size_t zcol = 0;
    if (b < 1280) {
        int rel = b >> 8, rem = b & 255;
        src = w0 + (size_t)rel * 262144; dst = w0t;
        cols = 512; ldOut = XLW; zcol = (size_t)rel * 512;
        bx = rem & 15; by = rem >> 4;
    } else if (b < 2560) {
        b -= 1280;
        int rel = b >> 8, rem = b & 255;
        src = w1 + (size_t)rel * 262144; dst = w1t;
        cols = 512; ldOut = XLW; zcol = (size_t)rel * 512;
        bx = rem & 15; by = rem >> 4;
    } else if (b < 6656) {
        b -= 2560;
        src = s1; dst = s1t; cols = 2048; ldOut = 2048;
        bx = b & 63; by = b >> 6;
    } else if (b < 7680) {
        b -= 6656;
        src = s2; dst = s2t; cols = 512; ldOut = 2048;
        bx = b & 15; by = b >> 4;
    } else if (b < 7936) {
        b -= 7680;
        src = f1; dst = f1t; cols = 512; ldOut = 512;
        bx = b & 15; by = b >> 4;
    } else {
        b -= 7936;
        src = f2; dst = f2t; cols = 512; ldOut = 512;
        bx = b & 15; by = b >> 4;
    }
    __shared__ u16 tile[32][33];
    int c0 = bx * 32, r0 = by * 32;
    int tx = threadIdx.x & 31, ty = threadIdx.x >> 5;   // 256 threads
    #pragma unroll
    for (int i = 0; i < 4; ++i) {
        int rr = ty + i * 8;
        tile[rr][tx] = f2bf(src[(size_t)(r0 + rr) * cols + c0 + tx]);
    }
    __syncthreads();
    #pragma unroll
    for (int i = 0; i < 4; ++i) {
        int rr = ty + i * 8;
        dst[(size_t)(c0 + rr) * ldOut + zcol + r0 + tx] = tile[tx][rr];
    }
}

// ------- 128m x 64n BT-GEMM, dbuf LDS; grid (N/64, M/128) -------------------------------
// EPI: 0 none, 4 tanh. FOUT: fp32 direct store. GUARDS: m/n guards.
template<int EPI, bool FOUT, bool GUARDS>
__global__ __launch_bounds__(256)
void gemm_n64(const u16* __restrict__ A, const u16* __restrict__ Bt,
              void* __restrict__ Cv, int K, int lda, int ldb, int ldc,
              int mGuard, int nGuard)
{
    __shared__ u16 As[2][128 * 32];
    __shared__ u16 Bs[2][64 * 32];
    const int tid = threadIdx.x;
    const int wave = tid >> 6, lane = tid & 63;
    const int m0 = blockIdx.y * 128, n0 = blockIdx.x * 64;
    const int srow = lane >> 2;            // 16 rows per 1KB wave-stage
    const int skoff = (lane & 3) << 3;     // 4 chunks of 8 bf16
    const int fr = lane & 15, quad = lane >> 4;
    const int wm = (wave & 1) << 6;        // 0 / 64
    const int wn = (wave >> 1) << 5;       // 0 / 32
    float4v acc[4][2] = {};

    const u16* Abase = A  + (size_t)(m0 + srow) * lda + skoff;
    const u16* Bbase = Bt + (size_t)(n0 + srow) * ldb + skoff;

    auto stage = [&](int buf, int k0) {
        #pragma unroll
        for (int i = 0; i < 2; ++i) {
            const int rb = (wave + i * 4) << 4;   // A rows 0..127
            __builtin_amdgcn_global_load_lds(
                (const __attribute__((address_space(1))) unsigned int*)(Abase + (size_t)rb * lda + k0),
                (__attribute__((address_space(3))) unsigned int*)(&As[buf][rb * 32]), 16, 0, 0);
        }
        const int rbB = wave << 4;                // B rows 0..63
        __builtin_amdgcn_global_load_lds(
            (const __attribute__((address_space(1))) unsigned int*)(Bbase + (size_t)rbB * ldb + k0),
            (__attribute__((address_space(3))) unsigned int*)(&Bs[buf][rbB * 32]), 16, 0, 0);
    };
    auto compute = [&](int buf) {
        short8 a[4], b[2];
        #pragma unroll
        for (int t = 0; t < 4; ++t)
            a[t] = *(const short8*)(&As[buf][((wm + t * 16 + fr) << 5) + (quad << 3)]);
        #pragma unroll
        for (int t = 0; t < 2; ++t)
            b[t] = *(const short8*)(&Bs[buf][((wn + t * 16 + fr) << 5) + (quad << 3)]);
        #pragma unroll
        for (int i = 0; i < 4; ++i)
            #pragma unroll
            for (int j = 0; j < 2; ++j)
                acc[i][j] = __builtin_amdgcn_mfma_f32_16x16x32_bf16(a[i], b[j], acc[i][j], 0, 0, 0);
    };

    stage(0, 0);
    __syncthreads();
    int cur = 0;
    for (int k0 = 32; k0 < K; k0 += 32) {
        stage(cur ^ 1, k0);
        compute(cur);
        __syncthreads();
        cur ^= 1;
    }
    compute(cur);

    #pragma unroll
    for (int i = 0; i < 4; ++i) {
        #pragma unroll
        for (int j = 0; j < 2; ++j) {
            const int n = n0 + wn + j * 16 + fr;
            #pragma unroll
            for (int rg = 0; rg < 4; ++rg) {
                const int m = m0 + wm + i * 16 + (quad << 2) + rg;
                if (GUARDS && (m >= mGuard || n >= nGuard)) continue;
                float v = acc[i][j][rg];
                if (EPI == 4) v = fast_tanh(v);
                if (FOUT) ((float*)Cv)[(size_t)m * ldc + n] = v;
                else      ((u16*)Cv)[(size_t)m * ldc + n] = f2bf(v);
            }
        }
    }
}

// ------- 128x128 split-K BT-GEMM (MLP stages; small C so atomics are L2-cheap) ----------
__global__ __launch_bounds__(256)
void gemm_sk(const u16* __restrict__ A, const u16* __restrict__ Bt,
             float* __restrict__ Cf, int Kc, int lda, int ldb, int ldc)
{
    __shared__ u16 As[2][128 * 32];
    __shared__ u16 Bs[2][128 * 32];
    const int tid = threadIdx.x;
    const int wave = tid >> 6, lane = tid & 63;
    const int m0 = blockIdx.y * 128, n0 = blockIdx.x * 128;
    const int kb = blockIdx.z * Kc;
    const int srow = lane >> 2;
    const int skoff = (lane & 3) << 3;
    const int fr = lane & 15, quad = lane >> 4;
    const int wm = (wave & 1) << 6, wn = (wave >> 1) << 6;
    float4v acc[4][4] = {};

    const u16* Abase = A  + (size_t)(m0 + srow) * lda + skoff;
    const u16* Bbase = Bt + (size_t)(n0 + srow) * ldb + skoff;

    auto stage = [&](int buf, int k0) {
        #pragma unroll
        for (int i = 0; i < 2; ++i) {
            const int rb = (wave + i * 4) << 4;
            __builtin_amdgcn_global_load_lds(
                (const __attribute__((address_space(1))) unsigned int*)(Abase + (size_t)rb * lda + k0),
                (__attribute__((address_space(3))) unsigned int*)(&As[buf][rb * 32]), 16, 0, 0);
            __builtin_amdgcn_global_load_lds(
                (const __attribute__((address_space(1))) unsigned int*)(Bbase + (size_t)rb * ldb + k0),
                (__attribute__((address_space(3))) unsigned int*)(&Bs[buf][rb * 32]), 16, 0, 0);
        }
    };
    auto compute = [&](int buf) {
        short8 a[4], b[4];
        #pragma unroll
        for (int t = 0; t < 4; ++t)
            a[t] = *(const short8*)(&As[buf][((wm + t * 16 + fr) << 5) + (quad << 3)]);
        #pragma unroll
        for (int t = 0; t < 4; ++t)
            b[t] = *(const short8*)(&Bs[buf][((wn + t * 16 + fr) << 5) + (quad << 3)]);
        #pragma unroll
        for (int i = 0; i < 4; ++i)
            #pragma unroll
            for (int j = 0; j < 4; ++j)
                acc[i][j] = __builtin_amdgcn_mfma_f32_16x16x32_bf16(a[i], b[j], acc[i][j], 0, 0, 0);
    };

    stage(0, kb);
    __syncthreads();
    int cur = 0;
    for (int k0 = kb + 32; k0 < kb + Kc; k0 += 32) {
        stage(cur ^ 1, k0);
        compute(cur);
        __syncthreads();
        cur ^= 1;
    }
    compute(cur);

    #pragma unroll
    for (int i = 0; i < 4; ++i)
        #pragma unroll
        for (int j = 0; j < 4; ++j) {
            const int n = n0 + wn + j * 16 + fr;
            #pragma unroll
            for (int rg = 0; rg < 4; ++rg) {
                const int m = m0 + wm + i * 16 + (quad << 2) + rg;
                atomicAdd(&Cf[(size_t)m * ldc + n], acc[i][j][rg]);
            }
        }
}

// split-K epilogue: [bias] + act + bf16 store. ACT: 0=none, 1=relu, 3=tanh
template<int ACT, bool HASB>
__global__ void sk_ep(const float* __restrict__ Cf, const float* __restrict__ bias,
                      u16* __restrict__ outp, int Ncols, int total4) {
    int t = blockIdx.x * 256 + threadIdx.x;
    if (t >= total4) return;
    int i = t << 2;
    float4 v = *(const float4*)(Cf + i);
    if (HASB) {
        int col = i & (Ncols - 1);
        v.x += bias[col]; v.y += bias[col + 1]; v.z += bias[col + 2]; v.w += bias[col + 3];
    }
    if (ACT == 1) { v.x = fmaxf(v.x, 0.f); v.y = fmaxf(v.y, 0.f);
                    v.z = fmaxf(v.z, 0.f); v.w = fmaxf(v.w, 0.f); }
    if (ACT == 3) { v.x = fast_tanh(v.x); v.y = fast_tanh(v.y);
                    v.z = fast_tanh(v.z); v.w = fast_tanh(v.w); }
    ushort4 o = { f2bf(v.x), f2bf(v.y), f2bf(v.z), f2bf(v.w) };
    *(ushort4*)(outp + i) = o;
}

// ---------------- gather-aggregate: agg[n][r*512+d] = sum_e vals[r][e] * x[col][d] ------
__device__ __forceinline__ void fma8(float* acc, uint4 u, float val) {
    acc[0] = fmaf(val, __uint_as_float(u.x << 16), acc[0]);
    acc[1] = fmaf(val, __uint_as_float(u.x & 0xffff0000u), acc[1]);
    acc[2] = fmaf(val, __uint_as_float(u.y << 16), acc[2]);
    acc[3] = fmaf(val, __uint_as_float(u.y & 0xffff0000u), acc[3]);
    acc[4] = fmaf(val, __uint_as_float(u.z << 16), acc[4]);
    acc[5] = fmaf(val, __uint_as_float(u.z & 0xffff0000u), acc[5]);
    acc[6] = fmaf(val, __uint_as_float(u.w << 16), acc[6]);
    acc[7] = fmaf(val, __uint_as_float(u.w & 0xffff0000u), acc[7]);
}

__global__ __launch_bounds__(256)
void spmm_agg(const u16* __restrict__ x, const int* __restrict__ offs,
              const int* __restrict__ colS, const float* __restrict__ valS,
              u16* __restrict__ agg)
{
    const int wave = threadIdx.x >> 6, lane = threadIdx.x & 63;
    const int n = blockIdx.x * 4 + wave;
    if (n >= NNODES) return;
    const u16* xr = x + (lane << 3);
    #pragma unroll
    for (int r = 0; r < RREL; ++r) {
        int s = offs[r * (NNODES + 1) + n];
        const int e = offs[r * (NNODES + 1) + n + 1];
        const int*   cp = colS + (size_t)r * EEDGES;
        const float* vp = valS + (size_t)r * EEDGES;
        float acc[8] = {0.f, 0.f, 0.f, 0.f, 0.f, 0.f, 0.f, 0.f};
        while (s < e) {                    // depth-8 batches, wave-uniform guards
            int m = e - s; if (m > 8) m = 8;
            int   ct[8]; float vt[8]; uint4 u[8];
            #pragma unroll
            for (int t = 0; t < 8; ++t)
                if (t < m) { ct[t] = cp[s + t]; vt[t] = vp[s + t]; }
            #pragma unroll
            for (int t = 0; t < 8; ++t)
                if (t < m) u[t] = *(const uint4*)(xr + (size_t)ct[t] * DDIM);
            #pragma unroll
            for (int t = 0; t < 8; ++t)
                if (t < m) fma8(acc, u[t], vt[t]);
            s += 8;
        }
        uint4 o;
        o.x = (uint32_t)f2bf(acc[0]) | ((uint32_t)f2bf(acc[1]) << 16);
        o.y = (uint32_t)f2bf(acc[2]) | ((uint32_t)f2bf(acc[3]) << 16);
        o.z = (uint32_t)f2bf(acc[4]) | ((uint32_t)f2bf(acc[5]) << 16);
        o.w = (uint32_t)f2bf(acc[6]) | ((uint32_t)f2bf(acc[7]) << 16);
        *(uint4*)(agg + (size_t)n * XLW + (r << 9) + (lane << 3)) = o;
    }
}

// ---------------- frame_node gather (bf16 emb -> fp32 out) ----------------
__global__ void frame_gather(const u16* __restrict__ emb, const int* __restrict__ frame_list,
                             const int* __restrict__ gold, float* __restrict__ out) {
    int t = blockIdx.x * 256 + threadIdx.x;   // 32*64
    if (t >= 32 * 64) return;
    int b = t >> 6, lane = t & 63;
    int label = frame_list[b * 16 + gold[b]];
    const u16* src = emb + (size_t)label * DDIM + (lane << 3);
    float* dst = out + (size_t)b * OUTC + FRAMES + (lane << 3);
    float4 o0 = { bf2f(src[0]), bf2f(src[1]), bf2f(src[2]), bf2f(src[3]) };
    float4 o1 = { bf2f(src[4]), bf2f(src[5]), bf2f(src[6]), bf2f(src[7]) };
    *(float4*)(dst) = o0;
    *(float4*)(dst + 4) = o1;
}

extern "C" void kernel_launch(void* const* d_in, const int* in_sizes, int n_in,
                              void* d_out, int out_size, void* d_ws, size_t ws_size,
                              hipStream_t stream) {
    const float* target_span = (const float*)d_in[0];
    const float* frame_emb   = (const float*)d_in[1];
    const float* role_emb    = (const float*)d_in[2];
    const float* rel_W0      = (const float*)d_in[3];
    const float* rel_W1      = (const float*)d_in[4];
    const float* span_W1     = (const float*)d_in[5];
    const float* span_b1     = (const float*)d_in[6];
    const float* span_W2     = (const float*)d_in[7];
    const float* span_b2     = (const float*)d_in[8];
    const float* fp_W1       = (const float*)d_in[9];
    const float* fp_b1       = (const float*)d_in[10];
    const float* fp_W2       = (const float*)d_in[11];
    const float* fp_b2       = (const float*)d_in[12];
    const float* adj_vals    = (const float*)d_in[13];
    const int* fe_ids      = (const int*)d_in[14];
    const int* adj_rows    = (const int*)d_in[15];
    const int* adj_cols    = (const int*)d_in[16];
    const int* gold_id     = (const int*)d_in[17];
    const int* frame_list  = (const int*)d_in[18];
    float* out = (float*)d_out;

    char* ws = (char*)d_ws;
    size_t off = 0;
    auto take = [&](size_t bytes) -> char* {
        char* p = ws + off;
        off = (off + bytes + 255) & ~(size_t)255;
        return p;
    };
    u16* x      = (u16*)take((size_t)MPAD * DDIM * 2);
    u16* agg    = (u16*)take((size_t)MPAD * XLW * 2);
    u16* w0t    = (u16*)take((size_t)512 * XLW * 2);     // Wcat0^T: [512 n][2560 k]
    u16* w1t    = (u16*)take((size_t)512 * XLW * 2);
    u16* s1t    = (u16*)take((size_t)2048 * 2048 * 2);
    u16* s2t    = (u16*)take((size_t)512 * 2048 * 2);
    u16* f1t    = (u16*)take((size_t)512 * 512 * 2);
    u16* f2t    = (u16*)take((size_t)512 * 512 * 2);
    int* counts = (int*)take((size_t)RREL * NNODES * 4);
    int* offs   = (int*)take((size_t)RREL * (NNODES + 1) * 4);
    int* cursor = (int*)take((size_t)RREL * NNODES * 4);
    int* colS   = (int*)take((size_t)RREL * EEDGES * 4);
    float* valS = (float*)take((size_t)RREL * EEDGES * 4);
    u16* tsp    = (u16*)take((size_t)128 * 2048 * 2);
    u16* h1     = (u16*)take((size_t)128 * 2048 * 2);
    u16* tn     = (u16*)take((size_t)128 * 512 * 2);
    u16* h2     = (u16*)take((size_t)128 * 512 * 2);
    u16* Qb     = (u16*)take((size_t)128 * 512 * 2);
    float* CfAll = (float*)take((size_t)(128 * 2048 + 3 * 128 * 512) * 4);
    float* Cf1 = CfAll;
    float* Cf2 = Cf1 + 128 * 2048;
    float* Cf3 = Cf2 + 128 * 512;
    float* Cf4 = Cf3 + 128 * 512;

    hipMemsetAsync(counts, 0, (size_t)RREL * NNODES * 4, stream);
    hipMemsetAsync(CfAll, 0, (size_t)(128 * 2048 + 3 * 128 * 512) * 4, stream);

    // CSR build (shared by both layers)
    hist_k<<<(RREL * EEDGES + 255) / 256, 256, 0, stream>>>(adj_rows, counts);
    scan_offsets<<<RREL, 1024, 0, stream>>>(counts, offs, cursor);
    scatter_k<<<(RREL * EEDGES + 255) / 256, 256, 0, stream>>>(adj_rows, adj_cols, adj_vals,
                                                               cursor, colS, valS);
    // merged input/weight prep
    prep_all<<<TR_BASE + 8192, 256, 0, stream>>>(frame_emb, role_emb, fe_ids, target_span,
                                                 rel_W0, rel_W1, span_W1, span_W2, fp_W1, fp_W2,
                                                 x, tsp, w0t, w1t, s1t, s2t, f1t, f2t);

    // relGCN layer 1: gather-agg -> 128x64-tile GEMM (grid 8x88, K=2560) fused tanh
    spmm_agg<<<(NNODES + 3) / 4, 256, 0, stream>>>(x, offs, colS, valS, agg);
    gemm_n64<4, false, true><<<dim3(8, MPAD / 128), 256, 0, stream>>>(
        agg, w0t, x, XLW, XLW, XLW, 512, NNODES, 512);
    // relGCN layer 2
    spmm_agg<<<(NNODES + 3) / 4, 256, 0, stream>>>(x, offs, colS, valS, agg);
    gemm_n64<4, false, true><<<dim3(8, MPAD / 128), 256, 0, stream>>>(
        agg, w1t, x, XLW, XLW, XLW, 512, NNODES, 512);

    // span MLP chain via split-K (small C, atomics cheap) + epilogues
    gemm_sk<<<dim3(16, 1, 8), 256, 0, stream>>>(tsp, s1t, Cf1, 256, 2048, 2048, 2048);
    sk_ep<1, true><<<(128 * 2048 / 4 + 255) / 256, 256, 0, stream>>>(Cf1, span_b1, h1, 2048, 128 * 2048 / 4);
    gemm_sk<<<dim3(4, 1, 8), 256, 0, stream>>>(h1, s2t, Cf2, 256, 2048, 2048, 512);
    sk_ep<0, true><<<(128 * 512 / 4 + 255) / 256, 256, 0, stream>>>(Cf2, span_b2, tn, 512, 128 * 512 / 4);
    gemm_sk<<<dim3(4, 1, 4), 256, 0, stream>>>(tn, f1t, Cf3, 128, 512, 512, 512);
    sk_ep<1, true><<<(128 * 512 / 4 + 255) / 256, 256, 0, stream>>>(Cf3, fp_b1, h2, 512, 128 * 512 / 4);
    gemm_sk<<<dim3(4, 1, 4), 256, 0, stream>>>(h2, f2t, Cf4, 128, 512, 512, 512);
    sk_ep<3, true><<<(128 * 512 / 4 + 255) / 256, 256, 0, stream>>>(Cf4, fp_b2, Qb, 512, 128 * 512 / 4);

    // pred_frame_weight = Q @ emb^T: direct fp32 store into out[:, :1200] (m<32, n<1200)
    gemm_n64<0, true, true><<<dim3(19, 1), 256, 0, stream>>>(
        Qb, x, out, 512, 512, 512, OUTC, 32, FRAMES);
    // frame_node gather; writes out[:, 1200:1712] as fp32
    frame_gather<<<8, 256, 0, stream>>>(x, frame_list, gold_id, out);
}

// Round 7
// 485.892 us; speedup vs baseline: 1.2932x; 1.0971x over previous
//
#include <hip/hip_runtime.h>
#include <hip/hip_bf16.h>
#include <stdint.h>

typedef unsigned short u16;
typedef __attribute__((ext_vector_type(8))) short short8;
typedef __attribute__((ext_vector_type(4))) float float4v;

#define NNODES 11201
#define MPAD   11264
#define EEDGES 100000
#define RREL   5
#define DDIM   512
#define XLW    2560      // RREL*DDIM
#define FRAMES 1200
#define OUTC   1712      // FRAMES + DDIM

__device__ __forceinline__ float bf2f(u16 h) {
    return __uint_as_float(((uint32_t)h) << 16);
}
__device__ __forceinline__ u16 f2bf(float f) {
    uint32_t x = __float_as_uint(f);
    x += 0x7fffu + ((x >> 16) & 1u);   // RNE
    return (u16)(x >> 16);
}
__device__ __forceinline__ float fast_tanh(float v) {
    v = fminf(fmaxf(v, -10.f), 10.f);
    float ex = __expf(2.f * v);
    return (ex - 1.f) / (ex + 1.f);
}

// ---------------- CSR build ----------------
__global__ void hist_k(const int* __restrict__ rows, int* __restrict__ counts) {
    int tid = blockIdx.x * 256 + threadIdx.x;
    if (tid >= RREL * EEDGES) return;
    int r = tid / EEDGES;
    atomicAdd(&counts[r * NNODES + rows[tid]], 1);
}

// single-pass scan: 1024 threads, 11 elems/thread; writes offs AND cursor
__global__ __launch_bounds__(1024) void scan_offsets(const int* __restrict__ counts,
                                                     int* __restrict__ offs,
                                                     int* __restrict__ cursor) {
    const int PER = 11;          // 1024*11 = 11264 >= NNODES
    int r = blockIdx.x;
    const int* c = counts + (size_t)r * NNODES;
    int* o = offs + (size_t)r * (NNODES + 1);
    int* cur = cursor + (size_t)r * NNODES;
    __shared__ int wsum[16];
    const int lane = threadIdx.x & 63, wid = threadIdx.x >> 6;
    int base = threadIdx.x * PER;
    int v[PER];
    int s = 0;
    #pragma unroll
    for (int t = 0; t < PER; ++t) {
        int idx = base + t;
        v[t] = (idx < NNODES) ? c[idx] : 0;
        s += v[t];
    }
    int incl = s;
    #pragma unroll
    for (int d = 1; d < 64; d <<= 1) {
        int t = __shfl_up(incl, d, 64);
        if (lane >= d) incl += t;
    }
    if (lane == 63) wsum[wid] = incl;
    __syncthreads();
    if (wid == 0) {
        int wv = (lane < 16) ? wsum[lane] : 0;
        #pragma unroll
        for (int d = 1; d < 16; d <<= 1) {
            int t = __shfl_up(wv, d, 64);
            if (lane >= d) wv += t;
        }
        if (lane < 16) wsum[lane] = wv;
    }
    __syncthreads();
    int run = incl - s + ((wid > 0) ? wsum[wid - 1] : 0);   // exclusive prefix
    #pragma unroll
    for (int t = 0; t < PER; ++t) {
        int idx = base + t;
        if (idx < NNODES) { o[idx] = run; cur[idx] = run; }
        run += v[t];
    }
    if (threadIdx.x == 1023) o[NNODES] = run;
}

__global__ void scatter_k(const int* __restrict__ rows, const int* __restrict__ cols,
                          const float* __restrict__ vals, int* __restrict__ cursor,
                          int* __restrict__ colS, float* __restrict__ valS) {
    int tid = blockIdx.x * 256 + threadIdx.x;
    if (tid >= RREL * EEDGES) return;
    int r = tid / EEDGES;
    int row = rows[tid];
    int pos = atomicAdd(&cursor[r * NNODES + row], 1);
    colS[(size_t)r * EEDGES + pos] = cols[tid];
    valS[(size_t)r * EEDGES + pos] = vals[tid];
}

// ------- merged prep: x assembly + tsp pad + all 6 weight transposes, one dispatch ------
#define BX_BLOCKS 5601                 // ceil(NNODES*128/256)
#define TSP_BLOCKS 256
#define TR_BASE (BX_BLOCKS + TSP_BLOCKS)
__global__ void prep_all(const float* __restrict__ frame_emb,
                         const float* __restrict__ role_emb,
                         const int* __restrict__ fe_ids,
                         const float* __restrict__ ts,
                         const float* __restrict__ w0, const float* __restrict__ w1,
                         const float* __restrict__ s1, const float* __restrict__ s2,
                         const float* __restrict__ f1, const float* __restrict__ f2,
                         u16* __restrict__ x, u16* __restrict__ tsp,
                         u16* __restrict__ w0t, u16* __restrict__ w1t,
                         u16* __restrict__ s1t, u16* __restrict__ s2t,
                         u16* __restrict__ f1t, u16* __restrict__ f2t) {
    int bid = blockIdx.x;
    if (bid < BX_BLOCKS) {
        int t = bid * 256 + threadIdx.x;
        int row = t >> 7, c4 = (t & 127) << 2;
        if (row >= NNODES) return;
        const float* src = (row < FRAMES) ? (frame_emb + (size_t)row * DDIM)
                                          : (role_emb + (size_t)fe_ids[row - FRAMES] * DDIM);
        float4 v = *(const float4*)(src + c4);
        ushort4 o = { f2bf(v.x), f2bf(v.y), f2bf(v.z), f2bf(v.w) };
        *(ushort4*)(x + (size_t)row * DDIM + c4) = o;
        return;
    }
    if (bid < TR_BASE) {
        int t = (bid - BX_BLOCKS) * 256 + threadIdx.x;   // < 65536
        int row = t >> 9, c4 = (t & 511) << 2;
        ushort4 o = {0, 0, 0, 0};
        if (row < 32) {
            float4 v = *(const float4*)(ts + (size_t)row * 2048 + c4);
            o = ushort4{ f2bf(v.x), f2bf(v.y), f2bf(v.z), f2bf(v.w) };
        }
        *(ushort4*)(tsp + (size_t)row * 2048 + c4) = o;
        return;
    }
    int b = bid - TR_BASE;
    const float* src; u16* dst;
    int cols, ldOut, bx, by;
    size_t zcol = 0;
    if (b < 1280) {
        int rel = b >> 8, rem = b & 255;
        src = w0 + (size_t)rel * 262144; dst = w0t;
        cols = 512; ldOut = XLW; zcol = (size_t)rel * 512;
        bx = rem & 15; by = rem >> 4;
    } else if (b < 2560) {
        b -= 1280;
        int rel = b >> 8, rem = b & 255;
        src = w1 + (size_t)rel * 262144; dst = w1t;
        cols = 512; ldOut = XLW; zcol = (size_t)rel * 512;
        bx = rem & 15; by = rem >> 4;
    } else if (b < 6656) {
        b -= 2560;
        src = s1; dst = s1t; cols = 2048; ldOut = 2048;
        bx = b & 63; by = b >> 6;
    } else if (b < 7680) {
        b -= 6656;
        src = s2; dst = s2t; cols = 512; ldOut = 2048;
        bx = b & 15; by = b >> 4;
    } else if (b < 7936) {
        b -= 7680;
        src = f1; dst = f1t; cols = 512; ldOut = 512;
        bx = b & 15; by = b >> 4;
    } else {
        b -= 7936;
        src = f2; dst = f2t; cols = 512; ldOut = 512;
        bx = b & 15; by = b >> 4;
    }
    __shared__ u16 tile[32][33];
    int c0 = bx * 32, r0 = by * 32;
    int tx = threadIdx.x & 31, ty = threadIdx.x >> 5;   // 256 threads
    #pragma unroll
    for (int i = 0; i < 4; ++i) {
        int rr = ty + i * 8;
        tile[rr][tx] = f2bf(src[(size_t)(r0 + rr) * cols + c0 + tx]);
    }
    __syncthreads();
    #pragma unroll
    for (int i = 0; i < 4; ++i) {
        int rr = ty + i * 8;
        dst[(size_t)(c0 + rr) * ldOut + zcol + r0 + tx] = tile[tx][rr];
    }
}

// ------- 128m x 64n BT-GEMM, dbuf LDS; grid (M/128, N/64) — x=m fastest so all n-blocks
// of one m-block land on the SAME XCD (id = m + gridDim.x*n, gridDim.x % 8 == 0) --------
// EPI: 0 none, 4 tanh. FOUT: fp32 direct store. GUARDS: m/n guards.
template<int EPI, bool FOUT, bool GUARDS>
__global__ __launch_bounds__(256)
void gemm_n64(const u16* __restrict__ A, const u16* __restrict__ Bt,
              void* __restrict__ Cv, int K, int lda, int ldb, int ldc,
              int mGuard, int nGuard)
{
    __shared__ u16 As[2][128 * 32];
    __shared__ u16 Bs[2][64 * 32];
    const int tid = threadIdx.x;
    const int wave = tid >> 6, lane = tid & 63;
    const int m0 = blockIdx.x * 128, n0 = blockIdx.y * 64;
    const int srow = lane >> 2;            // 16 rows per 1KB wave-stage
    const int skoff = (lane & 3) << 3;     // 4 chunks of 8 bf16
    const int fr = lane & 15, quad = lane >> 4;
    const int wm = (wave & 1) << 6;        // 0 / 64
    const int wn = (wave >> 1) << 5;       // 0 / 32
    float4v acc[4][2] = {};

    const u16* Abase = A  + (size_t)(m0 + srow) * lda + skoff;
    const u16* Bbase = Bt + (size_t)(n0 + srow) * ldb + skoff;

    auto stage = [&](int buf, int k0) {
        #pragma unroll
        for (int i = 0; i < 2; ++i) {
            const int rb = (wave + i * 4) << 4;   // A rows 0..127
            __builtin_amdgcn_global_load_lds(
                (const __attribute__((address_space(1))) unsigned int*)(Abase + (size_t)rb * lda + k0),
                (__attribute__((address_space(3))) unsigned int*)(&As[buf][rb * 32]), 16, 0, 0);
        }
        const int rbB = wave << 4;                // B rows 0..63
        __builtin_amdgcn_global_load_lds(
            (const __attribute__((address_space(1))) unsigned int*)(Bbase + (size_t)rbB * ldb + k0),
            (__attribute__((address_space(3))) unsigned int*)(&Bs[buf][rbB * 32]), 16, 0, 0);
    };
    auto compute = [&](int buf) {
        short8 a[4], b[2];
        #pragma unroll
        for (int t = 0; t < 4; ++t)
            a[t] = *(const short8*)(&As[buf][((wm + t * 16 + fr) << 5) + (quad << 3)]);
        #pragma unroll
        for (int t = 0; t < 2; ++t)
            b[t] = *(const short8*)(&Bs[buf][((wn + t * 16 + fr) << 5) + (quad << 3)]);
        #pragma unroll
        for (int i = 0; i < 4; ++i)
            #pragma unroll
            for (int j = 0; j < 2; ++j)
                acc[i][j] = __builtin_amdgcn_mfma_f32_16x16x32_bf16(a[i], b[j], acc[i][j], 0, 0, 0);
    };

    stage(0, 0);
    __syncthreads();
    int cur = 0;
    for (int k0 = 32; k0 < K; k0 += 32) {
        stage(cur ^ 1, k0);
        compute(cur);
        __syncthreads();
        cur ^= 1;
    }
    compute(cur);

    #pragma unroll
    for (int i = 0; i < 4; ++i) {
        #pragma unroll
        for (int j = 0; j < 2; ++j) {
            const int n = n0 + wn + j * 16 + fr;
            #pragma unroll
            for (int rg = 0; rg < 4; ++rg) {
                const int m = m0 + wm + i * 16 + (quad << 2) + rg;
                if (GUARDS && (m >= mGuard || n >= nGuard)) continue;
                float v = acc[i][j][rg];
                if (EPI == 4) v = fast_tanh(v);
                if (FOUT) ((float*)Cv)[(size_t)m * ldc + n] = v;
                else      ((u16*)Cv)[(size_t)m * ldc + n] = f2bf(v);
            }
        }
    }
}

// ------- 128x128 split-K BT-GEMM (MLP stages; small C so atomics are L2-cheap) ----------
__global__ __launch_bounds__(256)
void gemm_sk(const u16* __restrict__ A, const u16* __restrict__ Bt,
             float* __restrict__ Cf, int Kc, int lda, int ldb, int ldc)
{
    __shared__ u16 As[2][128 * 32];
    __shared__ u16 Bs[2][128 * 32];
    const int tid = threadIdx.x;
    const int wave = tid >> 6, lane = tid & 63;
    const int m0 = blockIdx.y * 128, n0 = blockIdx.x * 128;
    const int kb = blockIdx.z * Kc;
    const int srow = lane >> 2;
    const int skoff = (lane & 3) << 3;
    const int fr = lane & 15, quad = lane >> 4;
    const int wm = (wave & 1) << 6, wn = (wave >> 1) << 6;
    float4v acc[4][4] = {};

    const u16* Abase = A  + (size_t)(m0 + srow) * lda + skoff;
    const u16* Bbase = Bt + (size_t)(n0 + srow) * ldb + skoff;

    auto stage = [&](int buf, int k0) {
        #pragma unroll
        for (int i = 0; i < 2; ++i) {
            const int rb = (wave + i * 4) << 4;
            __builtin_amdgcn_global_load_lds(
                (const __attribute__((address_space(1))) unsigned int*)(Abase + (size_t)rb * lda + k0),
                (__attribute__((address_space(3))) unsigned int*)(&As[buf][rb * 32]), 16, 0, 0);
            __builtin_amdgcn_global_load_lds(
                (const __attribute__((address_space(1))) unsigned int*)(Bbase + (size_t)rb * ldb + k0),
                (__attribute__((address_space(3))) unsigned int*)(&Bs[buf][rb * 32]), 16, 0, 0);
        }
    };
    auto compute = [&](int buf) {
        short8 a[4], b[4];
        #pragma unroll
        for (int t = 0; t < 4; ++t)
            a[t] = *(const short8*)(&As[buf][((wm + t * 16 + fr) << 5) + (quad << 3)]);
        #pragma unroll
        for (int t = 0; t < 4; ++t)
            b[t] = *(const short8*)(&Bs[buf][((wn + t * 16 + fr) << 5) + (quad << 3)]);
        #pragma unroll
        for (int i = 0; i < 4; ++i)
            #pragma unroll
            for (int j = 0; j < 4; ++j)
                acc[i][j] = __builtin_amdgcn_mfma_f32_16x16x32_bf16(a[i], b[j], acc[i][j], 0, 0, 0);
    };

    stage(0, kb);
    __syncthreads();
    int cur = 0;
    for (int k0 = kb + 32; k0 < kb + Kc; k0 += 32) {
        stage(cur ^ 1, k0);
        compute(cur);
        __syncthreads();
        cur ^= 1;
    }
    compute(cur);

    #pragma unroll
    for (int i = 0; i < 4; ++i)
        #pragma unroll
        for (int j = 0; j < 4; ++j) {
            const int n = n0 + wn + j * 16 + fr;
            #pragma unroll
            for (int rg = 0; rg < 4; ++rg) {
                const int m = m0 + wm + i * 16 + (quad << 2) + rg;
                atomicAdd(&Cf[(size_t)m * ldc + n], acc[i][j][rg]);
            }
        }
}

// split-K epilogue: [bias] + act + bf16 store. ACT: 0=none, 1=relu, 3=tanh
template<int ACT, bool HASB>
__global__ void sk_ep(const float* __restrict__ Cf, const float* __restrict__ bias,
                      u16* __restrict__ outp, int Ncols, int total4) {
    int t = blockIdx.x * 256 + threadIdx.x;
    if (t >= total4) return;
    int i = t << 2;
    float4 v = *(const float4*)(Cf + i);
    if (HASB) {
        int col = i & (Ncols - 1);
        v.x += bias[col]; v.y += bias[col + 1]; v.z += bias[col + 2]; v.w += bias[col + 3];
    }
    if (ACT == 1) { v.x = fmaxf(v.x, 0.f); v.y = fmaxf(v.y, 0.f);
                    v.z = fmaxf(v.z, 0.f); v.w = fmaxf(v.w, 0.f); }
    if (ACT == 3) { v.x = fast_tanh(v.x); v.y = fast_tanh(v.y);
                    v.z = fast_tanh(v.z); v.w = fast_tanh(v.w); }
    ushort4 o = { f2bf(v.x), f2bf(v.y), f2bf(v.z), f2bf(v.w) };
    *(ushort4*)(outp + i) = o;
}

// ---------------- gather-aggregate, one wave per (node, relation) ------------------------
__device__ __forceinline__ void fma8(float* acc, uint4 u, float val) {
    acc[0] = fmaf(val, __uint_as_float(u.x << 16), acc[0]);
    acc[1] = fmaf(val, __uint_as_float(u.x & 0xffff0000u), acc[1]);
    acc[2] = fmaf(val, __uint_as_float(u.y << 16), acc[2]);
    acc[3] = fmaf(val, __uint_as_float(u.y & 0xffff0000u), acc[3]);
    acc[4] = fmaf(val, __uint_as_float(u.z << 16), acc[4]);
    acc[5] = fmaf(val, __uint_as_float(u.z & 0xffff0000u), acc[5]);
    acc[6] = fmaf(val, __uint_as_float(u.w << 16), acc[6]);
    acc[7] = fmaf(val, __uint_as_float(u.w & 0xffff0000u), acc[7]);
}

__global__ __launch_bounds__(256)
void spmm_agg(const u16* __restrict__ x, const int* __restrict__ offs,
              const int* __restrict__ colS, const float* __restrict__ valS,
              u16* __restrict__ agg)
{
    const int wave = threadIdx.x >> 6, lane = threadIdx.x & 63;
    const int n = blockIdx.x * 4 + wave;
    const int r = blockIdx.y;
    if (n >= NNODES) return;
    const u16* xr = x + (lane << 3);
    int s = offs[r * (NNODES + 1) + n];
    const int e = offs[r * (NNODES + 1) + n + 1];
    const int*   cp = colS + (size_t)r * EEDGES;
    const float* vp = valS + (size_t)r * EEDGES;
    float acc[8] = {0.f, 0.f, 0.f, 0.f, 0.f, 0.f, 0.f, 0.f};
    while (s < e) {                    // depth-8 batches, wave-uniform guards
        int m = e - s; if (m > 8) m = 8;
        int   ct[8]; float vt[8]; uint4 u[8];
        #pragma unroll
        for (int t = 0; t < 8; ++t)
            if (t < m) { ct[t] = cp[s + t]; vt[t] = vp[s + t]; }
        #pragma unroll
        for (int t = 0; t < 8; ++t)
            if (t < m) u[t] = *(const uint4*)(xr + (size_t)ct[t] * DDIM);
        #pragma unroll
        for (int t = 0; t < 8; ++t)
            if (t < m) fma8(acc, u[t], vt[t]);
        s += 8;
    }
    uint4 o;
    o.x = (uint32_t)f2bf(acc[0]) | ((uint32_t)f2bf(acc[1]) << 16);
    o.y = (uint32_t)f2bf(acc[2]) | ((uint32_t)f2bf(acc[3]) << 16);
    o.z = (uint32_t)f2bf(acc[4]) | ((uint32_t)f2bf(acc[5]) << 16);
    o.w = (uint32_t)f2bf(acc[6]) | ((uint32_t)f2bf(acc[7]) << 16);
    *(uint4*)(agg + (size_t)n * XLW + (r << 9) + (lane << 3)) = o;
}

// ---------------- frame_node gather (bf16 emb -> fp32 out) ----------------
__global__ void frame_gather(const u16* __restrict__ emb, const int* __restrict__ frame_list,
                             const int* __restrict__ gold, float* __restrict__ out) {
    int t = blockIdx.x * 256 + threadIdx.x;   // 32*64
    if (t >= 32 * 64) return;
    int b = t >> 6, lane = t & 63;
    int label = frame_list[b * 16 + gold[b]];
    const u16* src = emb + (size_t)label * DDIM + (lane << 3);
    float* dst = out + (size_t)b * OUTC + FRAMES + (lane << 3);
    float4 o0 = { bf2f(src[0]), bf2f(src[1]), bf2f(src[2]), bf2f(src[3]) };
    float4 o1 = { bf2f(src[4]), bf2f(src[5]), bf2f(src[6]), bf2f(src[7]) };
    *(float4*)(dst) = o0;
    *(float4*)(dst + 4) = o1;
}

extern "C" void kernel_launch(void* const* d_in, const int* in_sizes, int n_in,
                              void* d_out, int out_size, void* d_ws, size_t ws_size,
                              hipStream_t stream) {
    const float* target_span = (const float*)d_in[0];
    const float* frame_emb   = (const float*)d_in[1];
    const float* role_emb    = (const float*)d_in[2];
    const float* rel_W0      = (const float*)d_in[3];
    const float* rel_W1      = (const float*)d_in[4];
    const float* span_W1     = (const float*)d_in[5];
    const float* span_b1     = (const float*)d_in[6];
    const float* span_W2     = (const float*)d_in[7];
    const float* span_b2     = (const float*)d_in[8];
    const float* fp_W1       = (const float*)d_in[9];
    const float* fp_b1       = (const float*)d_in[10];
    const float* fp_W2       = (const float*)d_in[11];
    const float* fp_b2       = (const float*)d_in[12];
    const float* adj_vals    = (const float*)d_in[13];
    const int* fe_ids      = (const int*)d_in[14];
    const int* adj_rows    = (const int*)d_in[15];
    const int* adj_cols    = (const int*)d_in[16];
    const int* gold_id     = (const int*)d_in[17];
    const int* frame_list  = (const int*)d_in[18];
    float* out = (float*)d_out;

    char* ws = (char*)d_ws;
    size_t off = 0;
    auto take = [&](size_t bytes) -> char* {
        char* p = ws + off;
        off = (off + bytes + 255) & ~(size_t)255;
        return p;
    };
    u16* x      = (u16*)take((size_t)MPAD * DDIM * 2);
    u16* agg    = (u16*)take((size_t)MPAD * XLW * 2);
    u16* w0t    = (u16*)take((size_t)512 * XLW * 2);     // Wcat0^T: [512 n][2560 k]
    u16* w1t    = (u16*)take((size_t)512 * XLW * 2);
    u16* s1t    = (u16*)take((size_t)2048 * 2048 * 2);
    u16* s2t    = (u16*)take((size_t)512 * 2048 * 2);
    u16* f1t    = (u16*)take((size_t)512 * 512 * 2);
    u16* f2t    = (u16*)take((size_t)512 * 512 * 2);
    int* counts = (int*)take((size_t)RREL * NNODES * 4);
    int* offs   = (int*)take((size_t)RREL * (NNODES + 1) * 4);
    int* cursor = (int*)take((size_t)RREL * NNODES * 4);
    int* colS   = (int*)take((size_t)RREL * EEDGES * 4);
    float* valS = (float*)take((size_t)RREL * EEDGES * 4);
    u16* tsp    = (u16*)take((size_t)128 * 2048 * 2);
    u16* h1     = (u16*)take((size_t)128 * 2048 * 2);
    u16* tn     = (u16*)take((size_t)128 * 512 * 2);
    u16* h2     = (u16*)take((size_t)128 * 512 * 2);
    u16* Qb     = (u16*)take((size_t)128 * 512 * 2);
    float* CfAll = (float*)take((size_t)(128 * 2048 + 3 * 128 * 512) * 4);
    float* Cf1 = CfAll;
    float* Cf2 = Cf1 + 128 * 2048;
    float* Cf3 = Cf2 + 128 * 512;
    float* Cf4 = Cf3 + 128 * 512;

    hipMemsetAsync(counts, 0, (size_t)RREL * NNODES * 4, stream);
    hipMemsetAsync(CfAll, 0, (size_t)(128 * 2048 + 3 * 128 * 512) * 4, stream);

    // CSR build (shared by both layers)
    hist_k<<<(RREL * EEDGES + 255) / 256, 256, 0, stream>>>(adj_rows, counts);
    scan_offsets<<<RREL, 1024, 0, stream>>>(counts, offs, cursor);
    scatter_k<<<(RREL * EEDGES + 255) / 256, 256, 0, stream>>>(adj_rows, adj_cols, adj_vals,
                                                               cursor, colS, valS);
    // merged input/weight prep
    prep_all<<<TR_BASE + 8192, 256, 0, stream>>>(frame_emb, role_emb, fe_ids, target_span,
                                                 rel_W0, rel_W1, span_W1, span_W2, fp_W1, fp_W2,
                                                 x, tsp, w0t, w1t, s1t, s2t, f1t, f2t);

    // relGCN layer 1: gather-agg (per node,rel) -> XCD-swizzled 128x64 GEMM, fused tanh
    spmm_agg<<<dim3((NNODES + 3) / 4, RREL), 256, 0, stream>>>(x, offs, colS, valS, agg);
    gemm_n64<4, false, true><<<dim3(MPAD / 128, 8), 256, 0, stream>>>(
        agg, w0t, x, XLW, XLW, XLW, 512, NNODES, 512);
    // relGCN layer 2
    spmm_agg<<<dim3((NNODES + 3) / 4, RREL), 256, 0, stream>>>(x, offs, colS, valS, agg);
    gemm_n64<4, false, true><<<dim3(MPAD / 128, 8), 256, 0, stream>>>(
        agg, w1t, x, XLW, XLW, XLW, 512, NNODES, 512);

    // span MLP chain via split-K (small C, atomics cheap) + epilogues
    gemm_sk<<<dim3(16, 1, 8), 256, 0, stream>>>(tsp, s1t, Cf1, 256, 2048, 2048, 2048);
    sk_ep<1, true><<<(128 * 2048 / 4 + 255) / 256, 256, 0, stream>>>(Cf1, span_b1, h1, 2048, 128 * 2048 / 4);
    gemm_sk<<<dim3(4, 1, 8), 256, 0, stream>>>(h1, s2t, Cf2, 256, 2048, 2048, 512);
    sk_ep<0, true><<<(128 * 512 / 4 + 255) / 256, 256, 0, stream>>>(Cf2, span_b2, tn, 512, 128 * 512 / 4);
    gemm_sk<<<dim3(4, 1, 4), 256, 0, stream>>>(tn, f1t, Cf3, 128, 512, 512, 512);
    sk_ep<1, true><<<(128 * 512 / 4 + 255) / 256, 256, 0, stream>>>(Cf3, fp_b1, h2, 512, 128 * 512 / 4);
    gemm_sk<<<dim3(4, 1, 4), 256, 0, stream>>>(h2, f2t, Cf4, 128, 512, 512, 512);
    sk_ep<3, true><<<(128 * 512 / 4 + 255) / 256, 256, 0, stream>>>(Cf4, fp_b2, Qb, 512, 128 * 512 / 4);

    // pred_frame_weight = Q @ emb^T: direct fp32 store into out[:, :1200] (m<32, n<1200)
    gemm_n64<0, true, true><<<dim3(1, 19), 256, 0, stream>>>(
        Qb, x, out, 512, 512, 512, OUTC, 32, FRAMES);
    // frame_node gather; writes out[:, 1200:1712] as fp32
    frame_gather<<<8, 256, 0, stream>>>(x, frame_list, gold_id, out);
}